// Round 8
// baseline (2305.120 us; speedup 1.0000x reference)
//
#include <hip/hip_runtime.h>

#define THREADS 256
#define NB 512
#define SEGCAP 6144

typedef __attribute__((ext_vector_type(8))) short short8;
typedef __attribute__((ext_vector_type(4))) float f32x4;

// ---------------------------------------------------------------- bf16 helpers (raw ushort storage)
__device__ __forceinline__ float bf2f(unsigned short u) {
    union { unsigned int i; float f; } v;
    v.i = ((unsigned int)u) << 16;
    return v.f;
}
__device__ __forceinline__ unsigned short f2bf(float f) {
    union { float f; unsigned int i; } v;
    v.f = f;
    unsigned int r = (v.i + 0x7FFFu + ((v.i >> 16) & 1u)) >> 16;  // RNE
    return (unsigned short)r;
}
__device__ __forceinline__ float4 ld4f(const float* p) {
    return *reinterpret_cast<const float4*>(p);
}
__device__ __forceinline__ float4 ld4f(const unsigned short* p) {
    ushort4 u = *reinterpret_cast<const ushort4*>(p);
    return make_float4(bf2f(u.x), bf2f(u.y), bf2f(u.z), bf2f(u.w));
}

// ---------------------------------------------------------------- edge accessor (int32 or int64 payload)
__device__ __forceinline__ int edge_get(const int* base, int E, int mode, int which, int e) {
    size_t idx = (size_t)which * (size_t)E + (size_t)e;
    return mode ? base[2 * idx] : base[idx];
}

__global__ __launch_bounds__(256) void k_detect(const int* __restrict__ e, int E,
                                                int* __restrict__ mode) {
    __shared__ int nz;
    if (threadIdx.x == 0) nz = 0;
    __syncthreads();
    int lim = 2 * E;
    if (lim > 8192) lim = 8192;
    for (int i = 1 + 2 * (int)threadIdx.x; i < lim; i += 512)
        if (e[i] != 0) nz = 1;
    __syncthreads();
    if (threadIdx.x == 0) *mode = (nz == 0) ? 1 : 0;
}

// ---------------------------------------------------------------- graph prep: bucket partition CSR build
__global__ __launch_bounds__(256) void k_hist(const int* __restrict__ eb, int E,
                                              const int* __restrict__ mode, int N, int CW, int epb,
                                              int* __restrict__ gcnt) {
    __shared__ int hist[NB];
    for (int i = threadIdx.x; i < NB; i += 256) hist[i] = 0;
    __syncthreads();
    int m = *mode;
    int e0 = blockIdx.x * epb;
    int e1 = min(e0 + epb, E);
    for (int e = e0 + threadIdx.x; e < e1; e += 256) {
        int c = edge_get(eb, E, m, 1, e);
        if ((unsigned)c < (unsigned)N) atomicAdd(&hist[c / CW], 1);
    }
    __syncthreads();
    for (int i = threadIdx.x; i < NB; i += 256)
        if (hist[i]) atomicAdd(&gcnt[i], hist[i]);
}

__global__ __launch_bounds__(NB) void k_bscan(const int* __restrict__ gcnt,
                                              int* __restrict__ gbase, int* __restrict__ gcursor) {
    __shared__ int s[NB];
    int t = threadIdx.x;
    int v = gcnt[t];
    s[t] = v;
    __syncthreads();
    for (int off = 1; off < NB; off <<= 1) {
        int add = (t >= off) ? s[t - off] : 0;
        __syncthreads();
        s[t] += add;
        __syncthreads();
    }
    gbase[t] = s[t] - v;
    gcursor[t] = s[t] - v;
}

__global__ __launch_bounds__(256) void k_part(const int* __restrict__ eb, int E,
                                              const int* __restrict__ mode, int N, int CW, int epb,
                                              int* __restrict__ gcursor, uint2* __restrict__ ebuf) {
    __shared__ int hist[NB];
    __shared__ int base[NB];
    for (int i = threadIdx.x; i < NB; i += 256) hist[i] = 0;
    __syncthreads();
    int m = *mode;
    int e0 = blockIdx.x * epb;
    int e1 = min(e0 + epb, E);
    for (int e = e0 + threadIdx.x; e < e1; e += 256) {
        int c = edge_get(eb, E, m, 1, e);
        if ((unsigned)c < (unsigned)N) atomicAdd(&hist[c / CW], 1);
    }
    __syncthreads();
    for (int i = threadIdx.x; i < NB; i += 256) {
        int h = hist[i];
        base[i] = h ? atomicAdd(&gcursor[i], h) : 0;
        hist[i] = 0;  // reuse as local cursor
    }
    __syncthreads();
    for (int e = e0 + threadIdx.x; e < e1; e += 256) {
        int c = edge_get(eb, E, m, 1, e);
        if ((unsigned)c < (unsigned)N) {
            int r = edge_get(eb, E, m, 0, e);
            if ((unsigned)r >= (unsigned)N) r = 0;
            int b = c / CW;
            int li = atomicAdd(&hist[b], 1);
            ebuf[(size_t)base[b] + li] = make_uint2((unsigned)r, (unsigned)c);
        }
    }
}

__global__ __launch_bounds__(256) void k_build(const uint2* __restrict__ ebuf,
                                               const int* __restrict__ gbase,
                                               const int* __restrict__ gcnt, int N, int CW,
                                               int* __restrict__ cnt, int* __restrict__ offs,
                                               float* __restrict__ deg_inv, int* __restrict__ csr) {
    __shared__ int hist[256];
    __shared__ int pfx[256];
    __shared__ int seg[SEGCAP];
    const int b = blockIdx.x;
    const int col0 = b * CW;
    const int ncols = min(CW, N - col0);
    if (ncols <= 0) return;
    const int ebase = gbase[b], ecnt = gcnt[b];
    const int t = threadIdx.x;
    for (int i = t; i < 256; i += 256) hist[i] = 0;
    __syncthreads();
    for (int e = t; e < ecnt; e += 256) {
        uint2 rc = ebuf[(size_t)ebase + e];
        atomicAdd(&hist[rc.y - col0], 1);
    }
    __syncthreads();
    int v = (t < ncols) ? hist[t] : 0;
    pfx[t] = v;
    __syncthreads();
    for (int off = 1; off < 256; off <<= 1) {
        int add = (t >= off) ? pfx[t - off] : 0;
        __syncthreads();
        pfx[t] += add;
        __syncthreads();
    }
    int excl = pfx[t] - v;
    if (t < ncols) {
        cnt[col0 + t] = v;
        offs[col0 + t] = ebase + excl;
        deg_inv[col0 + t] = (v > 0) ? 1.0f / (float)v : 0.0f;
    }
    __syncthreads();
    if (t < 256) hist[t] = (t < ncols) ? excl : 0;  // reuse as per-col cursor (bucket-local)
    __syncthreads();
    if (ecnt <= SEGCAP) {
        for (int e = t; e < ecnt; e += 256) {
            uint2 rc = ebuf[(size_t)ebase + e];
            int li = atomicAdd(&hist[rc.y - col0], 1);
            seg[li] = (int)rc.x;
        }
        __syncthreads();
        for (int e = t; e < ecnt; e += 256) csr[(size_t)ebase + e] = seg[e];
    } else {  // statistical overflow fallback
        for (int e = t; e < ecnt; e += 256) {
            uint2 rc = ebuf[(size_t)ebase + e];
            int li = atomicAdd(&hist[rc.y - col0], 1);
            csr[(size_t)ebase + li] = (int)rc.x;
        }
    }
}

// ---------------------------------------------------------------- weight prep (bf16, transposed)
__global__ __launch_bounds__(256) void k_prep_wqk(const float* __restrict__ Wq,
                                                  const float* __restrict__ Wk,
                                                  unsigned short* __restrict__ WqkT) {
    int i = blockIdx.x * 256 + threadIdx.x;  // 512*128
    if (i < 512 * 128) {
        int oc = i >> 7, k = i & 127;
        float v = (oc < 256) ? Wq[k * 256 + oc] : Wk[k * 256 + (oc - 256)];
        WqkT[i] = f2bf(v);
    }
}

__global__ __launch_bounds__(256) void k_prep_wo(const float* __restrict__ Wo,
                                                 unsigned short* __restrict__ WoT) {
    int i = blockIdx.x * 256 + threadIdx.x;  // 1280*128
    if (i < 1280 * 128) {
        int r = i >> 7, j = i & 127;
        WoT[(size_t)j * 1280 + r] = f2bf(Wo[i]);
    }
}

// ---------------------------------------------------------------- Q/K proj + row L2-norm (MFMA, atomic-free)
__global__ __launch_bounds__(256) void k_proj(const float* __restrict__ x,
                                              const unsigned short* __restrict__ WqkT,
                                              const float* __restrict__ bq,
                                              const float* __restrict__ bk,
                                              unsigned short* __restrict__ qs,
                                              unsigned short* __restrict__ ks, int N) {
    __shared__ unsigned short xs[64 * 128];  // 16 KB input staging
    __shared__ unsigned short os[64 * 256];  // 32 KB output staging
    const int t = threadIdx.x;
    const int n0 = blockIdx.x * 64;
#pragma unroll
    for (int i = 0; i < 4; i++) {
        int chunk = i * 256 + t;
        int r = chunk >> 4, c0 = (chunk & 15) * 8;
        float4 a0 = make_float4(0.f, 0.f, 0.f, 0.f), a1 = a0;
        if (n0 + r < N) {
            a0 = ld4f(&x[(size_t)(n0 + r) * 128 + c0]);
            a1 = ld4f(&x[(size_t)(n0 + r) * 128 + c0 + 4]);
        }
        short8 v = {(short)f2bf(a0.x), (short)f2bf(a0.y), (short)f2bf(a0.z), (short)f2bf(a0.w),
                    (short)f2bf(a1.x), (short)f2bf(a1.y), (short)f2bf(a1.z), (short)f2bf(a1.w)};
        int byte = r * 256 + ((c0 * 2) ^ ((r & 7) << 4));
        *reinterpret_cast<short8*>(reinterpret_cast<char*>(xs) + byte) = v;
    }
    __syncthreads();
    const int w = t >> 6, l = t & 63, lrow = l & 15, lhi = l >> 4;
    f32x4 acc[4][8];
    const f32x4 fz = {0.f, 0.f, 0.f, 0.f};
#pragma unroll
    for (int mt = 0; mt < 4; mt++)
#pragma unroll
        for (int nt = 0; nt < 8; nt++) acc[mt][nt] = fz;

    for (int kk = 0; kk < 4; kk++) {
        int kb = kk * 32 + lhi * 8;
        short8 af[4];
#pragma unroll
        for (int mt = 0; mt < 4; mt++) {
            int r = mt * 16 + lrow;
            af[mt] = *reinterpret_cast<const short8*>(
                reinterpret_cast<const char*>(xs) + r * 256 + ((kb * 2) ^ ((r & 7) << 4)));
        }
#pragma unroll
        for (int nt = 0; nt < 8; nt++) {
            int oc = w * 128 + nt * 16 + lrow;
            short8 bf = *reinterpret_cast<const short8*>(&WqkT[(size_t)oc * 128 + kb]);
#pragma unroll
            for (int mt = 0; mt < 4; mt++)
                acc[mt][nt] = __builtin_amdgcn_mfma_f32_16x16x32_bf16(af[mt], bf, acc[mt][nt], 0, 0, 0);
        }
    }
    // bias
#pragma unroll
    for (int nt = 0; nt < 8; nt++) {
        int oc = w * 128 + nt * 16 + lrow;
        float b = (oc < 256) ? bq[oc] : bk[oc - 256];
#pragma unroll
        for (int mt = 0; mt < 4; mt++)
#pragma unroll
            for (int reg = 0; reg < 4; reg++) acc[mt][nt][reg] += b;
    }
    // row-norm in registers
    const int hc = (w & 1) * 128;
    float rv[4][4];
#pragma unroll
    for (int mt = 0; mt < 4; mt++) {
        float ss[4] = {0.f, 0.f, 0.f, 0.f};
#pragma unroll
        for (int nt = 0; nt < 8; nt++)
#pragma unroll
            for (int reg = 0; reg < 4; reg++) ss[reg] += acc[mt][nt][reg] * acc[mt][nt][reg];
#pragma unroll
        for (int m_ = 1; m_ < 16; m_ <<= 1)
#pragma unroll
            for (int reg = 0; reg < 4; reg++) ss[reg] += __shfl_xor(ss[reg], m_);
#pragma unroll
        for (int reg = 0; reg < 4; reg++) rv[mt][reg] = rsqrtf(ss[reg]);
    }
    for (int pass = 0; pass < 2; pass++) {
        if ((w >> 1) == pass) {
#pragma unroll
            for (int mt = 0; mt < 4; mt++)
#pragma unroll
                for (int reg = 0; reg < 4; reg++) {
                    int r = mt * 16 + lhi * 4 + reg;
#pragma unroll
                    for (int nt = 0; nt < 8; nt++)
                        os[r * 256 + hc + nt * 16 + lrow] = f2bf(acc[mt][nt][reg] * rv[mt][reg]);
                }
        }
        __syncthreads();
        unsigned short* dstg = pass ? ks : qs;
#pragma unroll
        for (int i = 0; i < 8; i++) {
            int chunk = i * 256 + t;
            int r = chunk >> 5, c = (chunk & 31) * 8;
            int n = n0 + r;
            if (n < N)
                *reinterpret_cast<short8*>(&dstg[(size_t)n * 256 + c]) =
                    *reinterpret_cast<const short8*>(&os[r * 256 + c]);
        }
        __syncthreads();
    }
}

// ---------------------------------------------------------------- ks_sum: 2-stage column reduction
__global__ __launch_bounds__(256) void k_colsum(const unsigned short* __restrict__ ks, int N,
                                                float* __restrict__ part) {
    const int t = threadIdx.x;
    const int stride = (N + 255) >> 8;
    int r0 = blockIdx.x * stride;
    int rend = min(r0 + stride, N);
    float s = 0.f;
    for (int n = r0; n < rend; n++) s += bf2f(ks[(size_t)n * 256 + t]);
    part[blockIdx.x * 256 + t] = s;
}

__global__ __launch_bounds__(256) void k_colsum2(const float* __restrict__ part,
                                                 float* __restrict__ ks_sum) {
    const int t = threadIdx.x;
    float s = 0.f;
    for (int b = 0; b < 256; b++) s += part[b * 256 + t];
    ks_sum[t] = s;
}

// ---------------------------------------------------------------- den = qs . ks_sum + N
__global__ __launch_bounds__(256) void k_den(const unsigned short* __restrict__ qs,
                                             const float* __restrict__ ks_sum,
                                             float* __restrict__ den, int N) {
    int w = threadIdx.x >> 6, lane = threadIdx.x & 63;
    int n = blockIdx.x * 4 + w;
    if (n >= N) return;
    float4 q = ld4f(&qs[(size_t)n * 256 + lane * 4]);
    float4 kv = *reinterpret_cast<const float4*>(&ks_sum[lane * 4]);
    float s = q.x * kv.x + q.y * kv.y + q.z * kv.z + q.w * kv.w;
#pragma unroll
    for (int off = 1; off < 32; off <<= 1) s += __shfl_xor(s, off);
    if ((lane & 31) == 0) den[n * 2 + (lane >> 5)] = s + (float)N;
}

// ---------------------------------------------------------------- kvsT = vs^T @ ks per head (MFMA split-K)
__device__ __forceinline__ short8 frag_ld(const unsigned short* tile, int kb, int col) {
    const char* b = reinterpret_cast<const char*>(tile);
    int cb = (col * 2) ^ (((kb >> 3) & 3) << 5);
    short8 r;
#pragma unroll
    for (int i = 0; i < 8; i++)
        r[i] = (short)*reinterpret_cast<const unsigned short*>(b + (kb + i) * 512 + cb);
    return r;
}

template <typename TV>
__global__ __launch_bounds__(256) void k_kvs2(const unsigned short* __restrict__ ks,
                                              const TV* __restrict__ vs, int vstride, int vmask,
                                              float* __restrict__ partial,
                                              float* __restrict__ pvsum, int rows_per, int N) {
    __shared__ unsigned short kt[32 * 256];
    __shared__ unsigned short vt[32 * 256];
    __shared__ float vred[8][256];
    const int t = threadIdx.x;
    const int w = t >> 6, l = t & 63, lrow = l & 15, lhi = l >> 4;
    const int h = w >> 1, mhalf = w & 1;
    const int r0 = blockIdx.x * rows_per;
    const int rend = min(r0 + rows_per, N);

    const f32x4 fz = {0.f, 0.f, 0.f, 0.f};
    f32x4 acc[4][8];
#pragma unroll
    for (int mt = 0; mt < 4; mt++)
#pragma unroll
        for (int nt = 0; nt < 8; nt++) acc[mt][nt] = fz;
    float vsum8[8] = {0.f, 0.f, 0.f, 0.f, 0.f, 0.f, 0.f, 0.f};

    for (int c0 = r0; c0 < rend; c0 += 32) {
#pragma unroll
        for (int i = 0; i < 4; i++) {
            int chunk = i * 256 + t;
            int n = chunk >> 5, cc = (chunk & 31) * 8;
            short8 v = {0, 0, 0, 0, 0, 0, 0, 0};
            if (c0 + n < rend)
                v = *reinterpret_cast<const short8*>(&ks[(size_t)(c0 + n) * 256 + cc]);
            *reinterpret_cast<short8*>(reinterpret_cast<char*>(kt) + n * 512 +
                                       ((cc * 2) ^ (((n >> 3) & 3) << 5))) = v;
        }
#pragma unroll
        for (int i = 0; i < 4; i++) {
            int chunk = i * 256 + t;
            int n = chunk >> 5, cc = (chunk & 31) * 8;
            float4 a0 = make_float4(0.f, 0.f, 0.f, 0.f), a1 = a0;
            if (c0 + n < rend) {
                a0 = ld4f(&vs[(size_t)(c0 + n) * vstride + (cc & vmask)]);
                a1 = ld4f(&vs[(size_t)(c0 + n) * vstride + ((cc + 4) & vmask)]);
            }
            unsigned short u0 = f2bf(a0.x), u1 = f2bf(a0.y), u2 = f2bf(a0.z), u3 = f2bf(a0.w);
            unsigned short u4 = f2bf(a1.x), u5 = f2bf(a1.y), u6 = f2bf(a1.z), u7 = f2bf(a1.w);
            vsum8[0] += bf2f(u0); vsum8[1] += bf2f(u1); vsum8[2] += bf2f(u2); vsum8[3] += bf2f(u3);
            vsum8[4] += bf2f(u4); vsum8[5] += bf2f(u5); vsum8[6] += bf2f(u6); vsum8[7] += bf2f(u7);
            short8 v = {(short)u0, (short)u1, (short)u2, (short)u3,
                        (short)u4, (short)u5, (short)u6, (short)u7};
            *reinterpret_cast<short8*>(reinterpret_cast<char*>(vt) + n * 512 +
                                       ((cc * 2) ^ (((n >> 3) & 3) << 5))) = v;
        }
        __syncthreads();
        {
            int kb = lhi * 8;
            short8 af[4];
#pragma unroll
            for (int mt = 0; mt < 4; mt++)
                af[mt] = frag_ld(vt, kb, h * 128 + mhalf * 64 + mt * 16 + lrow);
#pragma unroll
            for (int nt = 0; nt < 8; nt++) {
                short8 bf = frag_ld(kt, kb, h * 128 + nt * 16 + lrow);
#pragma unroll
                for (int mt = 0; mt < 4; mt++)
                    acc[mt][nt] =
                        __builtin_amdgcn_mfma_f32_16x16x32_bf16(af[mt], bf, acc[mt][nt], 0, 0, 0);
            }
        }
        __syncthreads();
    }
    float* pb = &partial[((size_t)blockIdx.x * 2 + h) * 16384];
#pragma unroll
    for (int mt = 0; mt < 4; mt++)
#pragma unroll
        for (int reg = 0; reg < 4; reg++) {
            int c_local = mhalf * 64 + mt * 16 + lhi * 4 + reg;
#pragma unroll
            for (int nt = 0; nt < 8; nt++) pb[c_local * 128 + nt * 16 + lrow] = acc[mt][nt][reg];
        }
    {
        int cc = (t & 31) * 8;
#pragma unroll
        for (int j = 0; j < 8; j++) vred[t >> 5][cc + j] = vsum8[j];
        __syncthreads();
        float s = 0.f;
#pragma unroll
        for (int r = 0; r < 8; r++) s += vred[r][t];
        pvsum[blockIdx.x * 256 + t] = s;
    }
}

// fused kvsT + vs_sum reduction
__global__ __launch_bounds__(256) void k_kvred(const float* __restrict__ partial,
                                               const float* __restrict__ pvsum, int S,
                                               unsigned short* __restrict__ kvsT,
                                               float* __restrict__ vs_sum) {
    if (blockIdx.x == 128) {
        int c = threadIdx.x;
        float s = 0.f;
        for (int i = 0; i < S; i++) s += pvsum[i * 256 + c];
        vs_sum[c] = s;
        return;
    }
    int e = blockIdx.x * 256 + threadIdx.x;  // 32768 elems
    float s = 0.f;
    for (int i = 0; i < S; i++) s += partial[(size_t)i * 32768 + e];
    kvsT[e] = f2bf(s);
}

// ---------------------------------------------------------------- fused per-hop kernel:
// phase1: attn = qs@kvsT (MFMA); gather: sm = 0.5*deg_inv*sum prev[src] (wave-per-row);
// phase2: sm += (attn+vs_sum)/den; writeback sm->cur; phase3: out += 0.5*sm@WoT(tblk)
template <typename TV>
__global__ __launch_bounds__(256) void k_fused(const unsigned short* __restrict__ qs,
                                               const unsigned short* __restrict__ kvsT,
                                               const float* __restrict__ vs_sum,
                                               const float* __restrict__ den,
                                               const TV* __restrict__ prev,
                                               const int* __restrict__ csr_src,
                                               const int* __restrict__ offs,
                                               const int* __restrict__ cnt,
                                               const float* __restrict__ deg_inv,
                                               unsigned short* __restrict__ cur,
                                               const unsigned short* __restrict__ WoT,
                                               float* __restrict__ out, int tblk, int N) {
    __shared__ unsigned short sm[64 * 256];
    const int t = threadIdx.x;
    const int n0 = blockIdx.x * 64;
    // stage qs tile (64 x 256), swizzled
#pragma unroll
    for (int i = 0; i < 8; i++) {
        int chunk = i * 256 + t;
        int r = chunk >> 5, c0 = (chunk & 31) * 8;
        short8 v = {0, 0, 0, 0, 0, 0, 0, 0};
        if (n0 + r < N) v = *reinterpret_cast<const short8*>(&qs[(size_t)(n0 + r) * 256 + c0]);
        *reinterpret_cast<short8*>(reinterpret_cast<char*>(sm) + r * 512 +
                                   ((c0 * 2) ^ ((r & 7) << 4))) = v;
    }
    __syncthreads();
    const int w = t >> 6, l = t & 63, lrow = l & 15, lhi = l >> 4;
    const int h = w >> 1, jh = w & 1;
    const f32x4 fz = {0.f, 0.f, 0.f, 0.f};
    f32x4 acc[4][4];
#pragma unroll
    for (int mt = 0; mt < 4; mt++)
#pragma unroll
        for (int nt = 0; nt < 4; nt++) acc[mt][nt] = fz;

    for (int kk = 0; kk < 4; kk++) {
        int kb = kk * 32 + lhi * 8;
        short8 af[4];
#pragma unroll
        for (int mt = 0; mt < 4; mt++) {
            int r = mt * 16 + lrow;
            af[mt] = *reinterpret_cast<const short8*>(
                reinterpret_cast<const char*>(sm) + r * 512 +
                (((h * 128 + kb) * 2) ^ ((r & 7) << 4)));
        }
#pragma unroll
        for (int nt = 0; nt < 4; nt++) {
            int c = jh * 64 + nt * 16 + lrow;
            short8 bf = *reinterpret_cast<const short8*>(&kvsT[((size_t)h * 128 + c) * 128 + kb]);
#pragma unroll
            for (int mt = 0; mt < 4; mt++)
                acc[mt][nt] = __builtin_amdgcn_mfma_f32_16x16x32_bf16(af[mt], bf, acc[mt][nt], 0, 0, 0);
        }
    }
    __syncthreads();  // done reading qs from sm
    // gather into sm: wave w owns rows w*16..w*16+15; lane l owns 8 bytes of the 512B row
    for (int i = 0; i < 16; i++) {
        int r = (w << 4) + i;
        int n = n0 + r;
        char* dst = reinterpret_cast<char*>(sm) + r * 512;
        const int swz = (r & 7) << 4;
        if (n < N) {
            const int start = offs[n];
            int e = start;
            const int eend = start + cnt[n];
            if constexpr (sizeof(TV) == 2) {
                const int co = l * 4;
                float a0 = 0.f, a1 = 0.f, a2 = 0.f, a3 = 0.f;
                for (; e + 8 <= eend; e += 8) {
                    int s[8];
#pragma unroll
                    for (int k = 0; k < 8; k++) s[k] = csr_src[e + k];
                    ushort4 u[8];
#pragma unroll
                    for (int k = 0; k < 8; k++)
                        u[k] = *reinterpret_cast<const ushort4*>(&prev[(size_t)s[k] * 256 + co]);
#pragma unroll
                    for (int k = 0; k < 8; k++) {
                        a0 += bf2f(u[k].x); a1 += bf2f(u[k].y);
                        a2 += bf2f(u[k].z); a3 += bf2f(u[k].w);
                    }
                }
                for (; e < eend; e++) {
                    ushort4 u =
                        *reinterpret_cast<const ushort4*>(&prev[(size_t)csr_src[e] * 256 + co]);
                    a0 += bf2f(u.x); a1 += bf2f(u.y); a2 += bf2f(u.z); a3 += bf2f(u.w);
                }
                float sc = 0.5f * deg_inv[n];
                ushort4 o;
                o.x = f2bf(a0 * sc); o.y = f2bf(a1 * sc);
                o.z = f2bf(a2 * sc); o.w = f2bf(a3 * sc);
                *reinterpret_cast<ushort4*>(dst + ((8 * l) ^ swz)) = o;
            } else {
                const int co = l * 2;
                float a0 = 0.f, a1 = 0.f;
                for (; e + 8 <= eend; e += 8) {
                    int s[8];
#pragma unroll
                    for (int k = 0; k < 8; k++) s[k] = csr_src[e + k];
                    float2 u[8];
#pragma unroll
                    for (int k = 0; k < 8; k++)
                        u[k] = *reinterpret_cast<const float2*>(&prev[(size_t)s[k] * 128 + co]);
#pragma unroll
                    for (int k = 0; k < 8; k++) { a0 += u[k].x; a1 += u[k].y; }
                }
                for (; e < eend; e++) {
                    float2 u =
                        *reinterpret_cast<const float2*>(&prev[(size_t)csr_src[e] * 128 + co]);
                    a0 += u.x; a1 += u.y;
                }
                float sc = 0.5f * deg_inv[n];
                ushort2 o;
                o.x = f2bf(a0 * sc); o.y = f2bf(a1 * sc);
                *reinterpret_cast<ushort2*>(dst + ((4 * l) ^ swz)) = o;
                *reinterpret_cast<ushort2*>(dst + ((256 + 4 * l) ^ swz)) = o;
            }
        } else {
            *reinterpret_cast<ushort4*>(dst + ((8 * l) ^ swz)) = make_ushort4(0, 0, 0, 0);
        }
    }
    __syncthreads();
    // phase2: sm += (attn + vs_sum)/den  (all in LDS)
#pragma unroll
    for (int mt = 0; mt < 4; mt++) {
#pragma unroll
        for (int reg = 0; reg < 4; reg++) {
            int r = mt * 16 + lhi * 4 + reg;
            int n = n0 + r;
            if (n < N) {
                float idn = 1.0f / den[n * 2 + h];
#pragma unroll
                for (int nt = 0; nt < 4; nt++) {
                    int c = h * 128 + jh * 64 + nt * 16 + lrow;
                    unsigned short* sp = reinterpret_cast<unsigned short*>(
                        reinterpret_cast<char*>(sm) + r * 512 + ((c * 2) ^ ((r & 7) << 4)));
                    float v = bf2f(*sp) + (acc[mt][nt][reg] + vs_sum[c]) * idn;
                    *sp = f2bf(v);
                }
            }
        }
    }
    __syncthreads();
    // writeback sm -> cur (coalesced)
#pragma unroll
    for (int i = 0; i < 8; i++) {
        int chunk = i * 256 + t;
        int r = chunk >> 5, c0 = (chunk & 31) * 8;
        int n = n0 + r;
        if (n < N)
            *reinterpret_cast<short8*>(&cur[(size_t)n * 256 + c0]) =
                *reinterpret_cast<const short8*>(reinterpret_cast<const char*>(sm) + r * 512 +
                                                 ((c0 * 2) ^ ((r & 7) << 4)));
    }
    // phase3: out += 0.5 * sm @ WoT(tblk)   (sm reads only; no barrier needed after writeback)
    f32x4 acc2[4][2];
#pragma unroll
    for (int mt = 0; mt < 4; mt++)
#pragma unroll
        for (int nt = 0; nt < 2; nt++) acc2[mt][nt] = fz;
    for (int kk = 0; kk < 8; kk++) {
        int kb = kk * 32 + lhi * 8;
        short8 af[4];
#pragma unroll
        for (int mt = 0; mt < 4; mt++) {
            int r = mt * 16 + lrow;
            af[mt] = *reinterpret_cast<const short8*>(
                reinterpret_cast<const char*>(sm) + r * 512 + ((kb * 2) ^ ((r & 7) << 4)));
        }
        int woff = (kb >> 7) * 640 + tblk * 128 + (kb & 127);
#pragma unroll
        for (int nt = 0; nt < 2; nt++) {
            int j = w * 32 + nt * 16 + lrow;
            short8 bf = *reinterpret_cast<const short8*>(&WoT[(size_t)j * 1280 + woff]);
#pragma unroll
            for (int mt = 0; mt < 4; mt++)
                acc2[mt][nt] = __builtin_amdgcn_mfma_f32_16x16x32_bf16(af[mt], bf, acc2[mt][nt], 0, 0, 0);
        }
    }
#pragma unroll
    for (int nt = 0; nt < 2; nt++) {
        int j = w * 32 + nt * 16 + lrow;
#pragma unroll
        for (int mt = 0; mt < 4; mt++)
#pragma unroll
            for (int reg = 0; reg < 4; reg++) {
                int n = n0 + mt * 16 + lhi * 4 + reg;
                if (n < N) out[(size_t)n * 128 + j] += 0.5f * acc2[mt][nt][reg];
            }
    }
}

// ---------------------------------------------------------------- term0: out = 0.5*([x|x]@Wo_0 + bias)
__global__ __launch_bounds__(256) void k_out0(const float* __restrict__ x,
                                              const unsigned short* __restrict__ WoT,
                                              const float* __restrict__ Wo_b,
                                              float* __restrict__ out, int N) {
    __shared__ unsigned short sm[64 * 256];
    const int t = threadIdx.x;
    const int n0 = blockIdx.x * 64;
#pragma unroll
    for (int i = 0; i < 8; i++) {
        int chunk = i * 256 + t;
        int r = chunk >> 5, c0 = (chunk & 31) * 8, cs = c0 & 127;
        float4 a0 = make_float4(0.f, 0.f, 0.f, 0.f), a1 = a0;
        if (n0 + r < N) {
            a0 = ld4f(&x[(size_t)(n0 + r) * 128 + cs]);
            a1 = ld4f(&x[(size_t)(n0 + r) * 128 + cs + 4]);
        }
        short8 v = {(short)f2bf(a0.x), (short)f2bf(a0.y), (short)f2bf(a0.z), (short)f2bf(a0.w),
                    (short)f2bf(a1.x), (short)f2bf(a1.y), (short)f2bf(a1.z), (short)f2bf(a1.w)};
        *reinterpret_cast<short8*>(reinterpret_cast<char*>(sm) + r * 512 +
                                   ((c0 * 2) ^ ((r & 7) << 4))) = v;
    }
    __syncthreads();
    const int w = t >> 6, l = t & 63, lrow = l & 15, lhi = l >> 4;
    const f32x4 fz = {0.f, 0.f, 0.f, 0.f};
    f32x4 acc2[4][2];
#pragma unroll
    for (int mt = 0; mt < 4; mt++)
#pragma unroll
        for (int nt = 0; nt < 2; nt++) acc2[mt][nt] = fz;
    for (int kk = 0; kk < 8; kk++) {
        int kb = kk * 32 + lhi * 8;
        short8 af[4];
#pragma unroll
        for (int mt = 0; mt < 4; mt++) {
            int r = mt * 16 + lrow;
            af[mt] = *reinterpret_cast<const short8*>(
                reinterpret_cast<const char*>(sm) + r * 512 + ((kb * 2) ^ ((r & 7) << 4)));
        }
        int woff = (kb >> 7) * 640 + (kb & 127);  // tblk = 0
#pragma unroll
        for (int nt = 0; nt < 2; nt++) {
            int j = w * 32 + nt * 16 + lrow;
            short8 bf = *reinterpret_cast<const short8*>(&WoT[(size_t)j * 1280 + woff]);
#pragma unroll
            for (int mt = 0; mt < 4; mt++)
                acc2[mt][nt] = __builtin_amdgcn_mfma_f32_16x16x32_bf16(af[mt], bf, acc2[mt][nt], 0, 0, 0);
        }
    }
#pragma unroll
    for (int nt = 0; nt < 2; nt++) {
        int j = w * 32 + nt * 16 + lrow;
        float b = Wo_b[j];
#pragma unroll
        for (int mt = 0; mt < 4; mt++)
#pragma unroll
            for (int reg = 0; reg < 4; reg++) {
                int n = n0 + mt * 16 + lhi * 4 + reg;
                if (n < N) out[(size_t)n * 128 + j] = 0.5f * (acc2[mt][nt][reg] + b);
            }
    }
}

// ================================================================ host
extern "C" void kernel_launch(void* const* d_in, const int* in_sizes, int n_in,
                              void* d_out, int out_size, void* d_ws, size_t ws_size,
                              hipStream_t stream) {
    const int N = in_sizes[0] / 128;
    const int E = in_sizes[1] / 2;
    const float* x = (const float*)d_in[0];
    const int* eraw = (const int*)d_in[1];
    const float* Wq_w = (const float*)d_in[2];
    const float* Wq_b = (const float*)d_in[3];
    const float* Wk_w = (const float*)d_in[4];
    const float* Wk_b = (const float*)d_in[5];
    const float* Wo_w = (const float*)d_in[6];
    const float* Wo_b = (const float*)d_in[7];
    float* out = (float*)d_out;

    char* p = (char*)d_ws;
    auto alloc = [&](size_t bytes) -> void* {
        void* r = (void*)p;
        p += (bytes + 255) & ~(size_t)255;
        return r;
    };
    unsigned short* qs = (unsigned short*)alloc((size_t)N * 256 * 2);
    unsigned short* ks = (unsigned short*)alloc((size_t)N * 256 * 2);
    unsigned short* bufA = (unsigned short*)alloc((size_t)N * 256 * 2);
    unsigned short* bufB = (unsigned short*)alloc((size_t)N * 256 * 2);
    float* deg_inv = (float*)alloc((size_t)N * 4);
    float* den = (float*)alloc((size_t)N * 2 * 4);
    float* ks_sum = (float*)alloc(256 * 4);
    float* vs_sum = (float*)alloc(256 * 4);
    float* colpart = (float*)alloc(256 * 256 * 4);
    unsigned short* WqkT = (unsigned short*)alloc(512 * 128 * 2);
    unsigned short* WoT = (unsigned short*)alloc(1280 * 128 * 2);
    unsigned short* kvsTb = (unsigned short*)alloc(32768 * 2);
    int* cnt = (int*)alloc((size_t)N * 4);
    int* offs = (int*)alloc((size_t)N * 4);
    int* gcnt = (int*)alloc(NB * 4);
    int* gbase = (int*)alloc(NB * 4);
    int* gcursor = (int*)alloc(NB * 4);
    int* mode = (int*)alloc(256);
    int* csr = (int*)alloc((size_t)E * 4);
    uint2* ebuf = (uint2*)alloc((size_t)E * 8);

    size_t used = (size_t)(p - (char*)d_ws);
    size_t rem = (ws_size > used + (1 << 20)) ? ws_size - used - (1 << 20) : 0;
    int S = (int)(rem / (32768 * 4 + 1024));
    if (S > 256) S = 256;
    if (S < 8) S = 8;
    float* partial = (float*)alloc((size_t)S * 32768 * 4);
    float* pvsum = (float*)alloc((size_t)S * 256 * 4);
    const int rows_per = (N + S - 1) / S;

    const int CW = (N + NB - 1) / NB;
    const int EBLK = 256;
    const int epb = (E + EBLK - 1) / EBLK;

    hipMemsetAsync(gcnt, 0, NB * 4, stream);

    k_detect<<<1, 256, 0, stream>>>(eraw, E, mode);
    k_hist<<<EBLK, 256, 0, stream>>>(eraw, E, mode, N, CW, epb, gcnt);
    k_bscan<<<1, NB, 0, stream>>>(gcnt, gbase, gcursor);
    k_part<<<EBLK, 256, 0, stream>>>(eraw, E, mode, N, CW, epb, gcursor, ebuf);
    k_build<<<NB, 256, 0, stream>>>(ebuf, gbase, gcnt, N, CW, cnt, offs, deg_inv, csr);

    k_prep_wqk<<<256, 256, 0, stream>>>(Wq_w, Wk_w, WqkT);
    k_prep_wo<<<640, 256, 0, stream>>>(Wo_w, WoT);

    const int nb64 = (N + 63) / 64;
    k_proj<<<nb64, 256, 0, stream>>>(x, WqkT, Wq_b, Wk_b, qs, ks, N);
    k_colsum<<<256, 256, 0, stream>>>(ks, N, colpart);
    k_colsum2<<<1, 256, 0, stream>>>(colpart, ks_sum);
    k_den<<<(N + 3) / 4, 256, 0, stream>>>(qs, ks_sum, den, N);
    k_out0<<<nb64, 256, 0, stream>>>(x, WoT, Wo_b, out, N);

    // hop 1: prev = x (f32, stride 128, head-broadcast)
    k_kvs2<float><<<S, 256, 0, stream>>>(ks, x, 128, 127, partial, pvsum, rows_per, N);
    k_kvred<<<129, 256, 0, stream>>>(partial, pvsum, S, kvsTb, vs_sum);
    k_fused<float><<<nb64, 256, 0, stream>>>(qs, kvsTb, vs_sum, den, x, csr, offs, cnt, deg_inv,
                                             bufA, WoT, out, 1, N);

    // hops 2..4
    unsigned short* prev = bufA;
    unsigned short* cur = bufB;
    for (int step = 2; step <= 4; step++) {
        k_kvs2<unsigned short><<<S, 256, 0, stream>>>(ks, prev, 256, 255, partial, pvsum, rows_per,
                                                      N);
        k_kvred<<<129, 256, 0, stream>>>(partial, pvsum, S, kvsTb, vs_sum);
        k_fused<unsigned short><<<nb64, 256, 0, stream>>>(qs, kvsTb, vs_sum, den, prev, csr, offs,
                                                          cnt, deg_inv, cur, WoT, out, step, N);
        unsigned short* tmp = prev;
        prev = cur;
        cur = tmp;
    }
}

// Round 9
// 1857.282 us; speedup vs baseline: 1.2411x; 1.2411x over previous
//
#include <hip/hip_runtime.h>

#define THREADS 256
#define NB 512
#define SEGCAP 6144

typedef __attribute__((ext_vector_type(8))) short short8;
typedef __attribute__((ext_vector_type(4))) float f32x4;

// ---------------------------------------------------------------- bf16 helpers (raw ushort storage)
__device__ __forceinline__ float bf2f(unsigned short u) {
    union { unsigned int i; float f; } v;
    v.i = ((unsigned int)u) << 16;
    return v.f;
}
__device__ __forceinline__ unsigned short f2bf(float f) {
    union { float f; unsigned int i; } v;
    v.f = f;
    unsigned int r = (v.i + 0x7FFFu + ((v.i >> 16) & 1u)) >> 16;  // RNE
    return (unsigned short)r;
}
__device__ __forceinline__ float4 ld4f(const float* p) {
    return *reinterpret_cast<const float4*>(p);
}
__device__ __forceinline__ float4 ld4f(const unsigned short* p) {
    ushort4 u = *reinterpret_cast<const ushort4*>(p);
    return make_float4(bf2f(u.x), bf2f(u.y), bf2f(u.z), bf2f(u.w));
}

// ---------------------------------------------------------------- edge accessor (int32 or int64 payload)
__device__ __forceinline__ int edge_get(const int* base, int E, int mode, int which, int e) {
    size_t idx = (size_t)which * (size_t)E + (size_t)e;
    return mode ? base[2 * idx] : base[idx];
}

__global__ __launch_bounds__(256) void k_detect(const int* __restrict__ e, int E,
                                                int* __restrict__ mode) {
    __shared__ int nz;
    if (threadIdx.x == 0) nz = 0;
    __syncthreads();
    int lim = 2 * E;
    if (lim > 8192) lim = 8192;
    for (int i = 1 + 2 * (int)threadIdx.x; i < lim; i += 512)
        if (e[i] != 0) nz = 1;
    __syncthreads();
    if (threadIdx.x == 0) *mode = (nz == 0) ? 1 : 0;
}

// ---------------------------------------------------------------- graph prep: bucket partition CSR build
__global__ __launch_bounds__(256) void k_hist(const int* __restrict__ eb, int E,
                                              const int* __restrict__ mode, int N, int CW, int epb,
                                              int* __restrict__ gcnt) {
    __shared__ int hist[NB];
    for (int i = threadIdx.x; i < NB; i += 256) hist[i] = 0;
    __syncthreads();
    int m = *mode;
    int e0 = blockIdx.x * epb;
    int e1 = min(e0 + epb, E);
    for (int e = e0 + threadIdx.x; e < e1; e += 256) {
        int c = edge_get(eb, E, m, 1, e);
        if ((unsigned)c < (unsigned)N) atomicAdd(&hist[c / CW], 1);
    }
    __syncthreads();
    for (int i = threadIdx.x; i < NB; i += 256)
        if (hist[i]) atomicAdd(&gcnt[i], hist[i]);
}

__global__ __launch_bounds__(NB) void k_bscan(const int* __restrict__ gcnt,
                                              int* __restrict__ gbase, int* __restrict__ gcursor) {
    __shared__ int s[NB];
    int t = threadIdx.x;
    int v = gcnt[t];
    s[t] = v;
    __syncthreads();
    for (int off = 1; off < NB; off <<= 1) {
        int add = (t >= off) ? s[t - off] : 0;
        __syncthreads();
        s[t] += add;
        __syncthreads();
    }
    gbase[t] = s[t] - v;
    gcursor[t] = s[t] - v;
}

__global__ __launch_bounds__(256) void k_part(const int* __restrict__ eb, int E,
                                              const int* __restrict__ mode, int N, int CW, int epb,
                                              int* __restrict__ gcursor, uint2* __restrict__ ebuf) {
    __shared__ int hist[NB];
    __shared__ int base[NB];
    for (int i = threadIdx.x; i < NB; i += 256) hist[i] = 0;
    __syncthreads();
    int m = *mode;
    int e0 = blockIdx.x * epb;
    int e1 = min(e0 + epb, E);
    for (int e = e0 + threadIdx.x; e < e1; e += 256) {
        int c = edge_get(eb, E, m, 1, e);
        if ((unsigned)c < (unsigned)N) atomicAdd(&hist[c / CW], 1);
    }
    __syncthreads();
    for (int i = threadIdx.x; i < NB; i += 256) {
        int h = hist[i];
        base[i] = h ? atomicAdd(&gcursor[i], h) : 0;
        hist[i] = 0;  // reuse as local cursor
    }
    __syncthreads();
    for (int e = e0 + threadIdx.x; e < e1; e += 256) {
        int c = edge_get(eb, E, m, 1, e);
        if ((unsigned)c < (unsigned)N) {
            int r = edge_get(eb, E, m, 0, e);
            if ((unsigned)r >= (unsigned)N) r = 0;
            int b = c / CW;
            int li = atomicAdd(&hist[b], 1);
            ebuf[(size_t)base[b] + li] = make_uint2((unsigned)r, (unsigned)c);
        }
    }
}

__global__ __launch_bounds__(256) void k_build(const uint2* __restrict__ ebuf,
                                               const int* __restrict__ gbase,
                                               const int* __restrict__ gcnt, int N, int CW,
                                               int* __restrict__ cnt, int* __restrict__ offs,
                                               float* __restrict__ deg_inv, int* __restrict__ csr) {
    __shared__ int hist[256];
    __shared__ int pfx[256];
    __shared__ int seg[SEGCAP];
    const int b = blockIdx.x;
    const int col0 = b * CW;
    const int ncols = min(CW, N - col0);
    if (ncols <= 0) return;
    const int ebase = gbase[b], ecnt = gcnt[b];
    const int t = threadIdx.x;
    for (int i = t; i < 256; i += 256) hist[i] = 0;
    __syncthreads();
    for (int e = t; e < ecnt; e += 256) {
        uint2 rc = ebuf[(size_t)ebase + e];
        atomicAdd(&hist[rc.y - col0], 1);
    }
    __syncthreads();
    int v = (t < ncols) ? hist[t] : 0;
    pfx[t] = v;
    __syncthreads();
    for (int off = 1; off < 256; off <<= 1) {
        int add = (t >= off) ? pfx[t - off] : 0;
        __syncthreads();
        pfx[t] += add;
        __syncthreads();
    }
    int excl = pfx[t] - v;
    if (t < ncols) {
        cnt[col0 + t] = v;
        offs[col0 + t] = ebase + excl;
        deg_inv[col0 + t] = (v > 0) ? 1.0f / (float)v : 0.0f;
    }
    __syncthreads();
    if (t < 256) hist[t] = (t < ncols) ? excl : 0;  // reuse as per-col cursor (bucket-local)
    __syncthreads();
    if (ecnt <= SEGCAP) {
        for (int e = t; e < ecnt; e += 256) {
            uint2 rc = ebuf[(size_t)ebase + e];
            int li = atomicAdd(&hist[rc.y - col0], 1);
            seg[li] = (int)rc.x;
        }
        __syncthreads();
        for (int e = t; e < ecnt; e += 256) csr[(size_t)ebase + e] = seg[e];
    } else {  // statistical overflow fallback
        for (int e = t; e < ecnt; e += 256) {
            uint2 rc = ebuf[(size_t)ebase + e];
            int li = atomicAdd(&hist[rc.y - col0], 1);
            csr[(size_t)ebase + li] = (int)rc.x;
        }
    }
}

// ---------------------------------------------------------------- weight prep (bf16, transposed)
__global__ __launch_bounds__(256) void k_prep_wqk(const float* __restrict__ Wq,
                                                  const float* __restrict__ Wk,
                                                  unsigned short* __restrict__ WqkT) {
    int i = blockIdx.x * 256 + threadIdx.x;  // 512*128
    if (i < 512 * 128) {
        int oc = i >> 7, k = i & 127;
        float v = (oc < 256) ? Wq[k * 256 + oc] : Wk[k * 256 + (oc - 256)];
        WqkT[i] = f2bf(v);
    }
}

__global__ __launch_bounds__(256) void k_prep_wo(const float* __restrict__ Wo,
                                                 unsigned short* __restrict__ WoT) {
    int i = blockIdx.x * 256 + threadIdx.x;  // 1280*128
    if (i < 1280 * 128) {
        int r = i >> 7, j = i & 127;
        WoT[(size_t)j * 1280 + r] = f2bf(Wo[i]);
    }
}

// ---------------------------------------------------------------- Q/K proj + row L2-norm (MFMA, atomic-free)
__global__ __launch_bounds__(256) void k_proj(const float* __restrict__ x,
                                              const unsigned short* __restrict__ WqkT,
                                              const float* __restrict__ bq,
                                              const float* __restrict__ bk,
                                              unsigned short* __restrict__ qs,
                                              unsigned short* __restrict__ ks, int N) {
    __shared__ unsigned short xs[64 * 128];  // 16 KB input staging
    __shared__ unsigned short os[64 * 256];  // 32 KB output staging
    const int t = threadIdx.x;
    const int n0 = blockIdx.x * 64;
#pragma unroll
    for (int i = 0; i < 4; i++) {
        int chunk = i * 256 + t;
        int r = chunk >> 4, c0 = (chunk & 15) * 8;
        float4 a0 = make_float4(0.f, 0.f, 0.f, 0.f), a1 = a0;
        if (n0 + r < N) {
            a0 = ld4f(&x[(size_t)(n0 + r) * 128 + c0]);
            a1 = ld4f(&x[(size_t)(n0 + r) * 128 + c0 + 4]);
        }
        short8 v = {(short)f2bf(a0.x), (short)f2bf(a0.y), (short)f2bf(a0.z), (short)f2bf(a0.w),
                    (short)f2bf(a1.x), (short)f2bf(a1.y), (short)f2bf(a1.z), (short)f2bf(a1.w)};
        int byte = r * 256 + ((c0 * 2) ^ ((r & 7) << 4));
        *reinterpret_cast<short8*>(reinterpret_cast<char*>(xs) + byte) = v;
    }
    __syncthreads();
    const int w = t >> 6, l = t & 63, lrow = l & 15, lhi = l >> 4;
    f32x4 acc[4][8];
    const f32x4 fz = {0.f, 0.f, 0.f, 0.f};
#pragma unroll
    for (int mt = 0; mt < 4; mt++)
#pragma unroll
        for (int nt = 0; nt < 8; nt++) acc[mt][nt] = fz;

    for (int kk = 0; kk < 4; kk++) {
        int kb = kk * 32 + lhi * 8;
        short8 af[4];
#pragma unroll
        for (int mt = 0; mt < 4; mt++) {
            int r = mt * 16 + lrow;
            af[mt] = *reinterpret_cast<const short8*>(
                reinterpret_cast<const char*>(xs) + r * 256 + ((kb * 2) ^ ((r & 7) << 4)));
        }
#pragma unroll
        for (int nt = 0; nt < 8; nt++) {
            int oc = w * 128 + nt * 16 + lrow;
            short8 bf = *reinterpret_cast<const short8*>(&WqkT[(size_t)oc * 128 + kb]);
#pragma unroll
            for (int mt = 0; mt < 4; mt++)
                acc[mt][nt] = __builtin_amdgcn_mfma_f32_16x16x32_bf16(af[mt], bf, acc[mt][nt], 0, 0, 0);
        }
    }
    // bias
#pragma unroll
    for (int nt = 0; nt < 8; nt++) {
        int oc = w * 128 + nt * 16 + lrow;
        float b = (oc < 256) ? bq[oc] : bk[oc - 256];
#pragma unroll
        for (int mt = 0; mt < 4; mt++)
#pragma unroll
            for (int reg = 0; reg < 4; reg++) acc[mt][nt][reg] += b;
    }
    // row-norm in registers
    const int hc = (w & 1) * 128;
    float rv[4][4];
#pragma unroll
    for (int mt = 0; mt < 4; mt++) {
        float ss[4] = {0.f, 0.f, 0.f, 0.f};
#pragma unroll
        for (int nt = 0; nt < 8; nt++)
#pragma unroll
            for (int reg = 0; reg < 4; reg++) ss[reg] += acc[mt][nt][reg] * acc[mt][nt][reg];
#pragma unroll
        for (int m_ = 1; m_ < 16; m_ <<= 1)
#pragma unroll
            for (int reg = 0; reg < 4; reg++) ss[reg] += __shfl_xor(ss[reg], m_);
#pragma unroll
        for (int reg = 0; reg < 4; reg++) rv[mt][reg] = rsqrtf(ss[reg]);
    }
    for (int pass = 0; pass < 2; pass++) {
        if ((w >> 1) == pass) {
#pragma unroll
            for (int mt = 0; mt < 4; mt++)
#pragma unroll
                for (int reg = 0; reg < 4; reg++) {
                    int r = mt * 16 + lhi * 4 + reg;
#pragma unroll
                    for (int nt = 0; nt < 8; nt++)
                        os[r * 256 + hc + nt * 16 + lrow] = f2bf(acc[mt][nt][reg] * rv[mt][reg]);
                }
        }
        __syncthreads();
        unsigned short* dstg = pass ? ks : qs;
#pragma unroll
        for (int i = 0; i < 8; i++) {
            int chunk = i * 256 + t;
            int r = chunk >> 5, c = (chunk & 31) * 8;
            int n = n0 + r;
            if (n < N)
                *reinterpret_cast<short8*>(&dstg[(size_t)n * 256 + c]) =
                    *reinterpret_cast<const short8*>(&os[r * 256 + c]);
        }
        __syncthreads();
    }
}

// ---------------------------------------------------------------- ks_sum: 2-stage column reduction
__global__ __launch_bounds__(256) void k_colsum(const unsigned short* __restrict__ ks, int N,
                                                float* __restrict__ part) {
    const int t = threadIdx.x;
    const int stride = (N + 255) >> 8;
    int r0 = blockIdx.x * stride;
    int rend = min(r0 + stride, N);
    float s = 0.f;
    for (int n = r0; n < rend; n++) s += bf2f(ks[(size_t)n * 256 + t]);
    part[blockIdx.x * 256 + t] = s;
}

__global__ __launch_bounds__(256) void k_colsum2(const float* __restrict__ part,
                                                 float* __restrict__ ks_sum) {
    const int t = threadIdx.x;
    float s = 0.f;
    for (int b = 0; b < 256; b++) s += part[b * 256 + t];
    ks_sum[t] = s;
}

// ---------------------------------------------------------------- den = qs . ks_sum + N
__global__ __launch_bounds__(256) void k_den(const unsigned short* __restrict__ qs,
                                             const float* __restrict__ ks_sum,
                                             float* __restrict__ den, int N) {
    int w = threadIdx.x >> 6, lane = threadIdx.x & 63;
    int n = blockIdx.x * 4 + w;
    if (n >= N) return;
    float4 q = ld4f(&qs[(size_t)n * 256 + lane * 4]);
    float4 kv = *reinterpret_cast<const float4*>(&ks_sum[lane * 4]);
    float s = q.x * kv.x + q.y * kv.y + q.z * kv.z + q.w * kv.w;
#pragma unroll
    for (int off = 1; off < 32; off <<= 1) s += __shfl_xor(s, off);
    if ((lane & 31) == 0) den[n * 2 + (lane >> 5)] = s + (float)N;
}

// ---------------------------------------------------------------- kvsT = vs^T @ ks per head (MFMA split-K)
__device__ __forceinline__ short8 frag_ld(const unsigned short* tile, int kb, int col) {
    const char* b = reinterpret_cast<const char*>(tile);
    int cb = (col * 2) ^ (((kb >> 3) & 3) << 5);
    short8 r;
#pragma unroll
    for (int i = 0; i < 8; i++)
        r[i] = (short)*reinterpret_cast<const unsigned short*>(b + (kb + i) * 512 + cb);
    return r;
}

template <typename TV>
__global__ __launch_bounds__(256) void k_kvs2(const unsigned short* __restrict__ ks,
                                              const TV* __restrict__ vs, int vstride, int vmask,
                                              float* __restrict__ partial,
                                              float* __restrict__ pvsum, int rows_per, int N) {
    __shared__ unsigned short kt[32 * 256];
    __shared__ unsigned short vt[32 * 256];
    __shared__ float vred[8][256];
    const int t = threadIdx.x;
    const int w = t >> 6, l = t & 63, lrow = l & 15, lhi = l >> 4;
    const int h = w >> 1, mhalf = w & 1;
    const int r0 = blockIdx.x * rows_per;
    const int rend = min(r0 + rows_per, N);

    const f32x4 fz = {0.f, 0.f, 0.f, 0.f};
    f32x4 acc[4][8];
#pragma unroll
    for (int mt = 0; mt < 4; mt++)
#pragma unroll
        for (int nt = 0; nt < 8; nt++) acc[mt][nt] = fz;
    float vsum8[8] = {0.f, 0.f, 0.f, 0.f, 0.f, 0.f, 0.f, 0.f};

    for (int c0 = r0; c0 < rend; c0 += 32) {
#pragma unroll
        for (int i = 0; i < 4; i++) {
            int chunk = i * 256 + t;
            int n = chunk >> 5, cc = (chunk & 31) * 8;
            short8 v = {0, 0, 0, 0, 0, 0, 0, 0};
            if (c0 + n < rend)
                v = *reinterpret_cast<const short8*>(&ks[(size_t)(c0 + n) * 256 + cc]);
            *reinterpret_cast<short8*>(reinterpret_cast<char*>(kt) + n * 512 +
                                       ((cc * 2) ^ (((n >> 3) & 3) << 5))) = v;
        }
#pragma unroll
        for (int i = 0; i < 4; i++) {
            int chunk = i * 256 + t;
            int n = chunk >> 5, cc = (chunk & 31) * 8;
            float4 a0 = make_float4(0.f, 0.f, 0.f, 0.f), a1 = a0;
            if (c0 + n < rend) {
                a0 = ld4f(&vs[(size_t)(c0 + n) * vstride + (cc & vmask)]);
                a1 = ld4f(&vs[(size_t)(c0 + n) * vstride + ((cc + 4) & vmask)]);
            }
            unsigned short u0 = f2bf(a0.x), u1 = f2bf(a0.y), u2 = f2bf(a0.z), u3 = f2bf(a0.w);
            unsigned short u4 = f2bf(a1.x), u5 = f2bf(a1.y), u6 = f2bf(a1.z), u7 = f2bf(a1.w);
            vsum8[0] += bf2f(u0); vsum8[1] += bf2f(u1); vsum8[2] += bf2f(u2); vsum8[3] += bf2f(u3);
            vsum8[4] += bf2f(u4); vsum8[5] += bf2f(u5); vsum8[6] += bf2f(u6); vsum8[7] += bf2f(u7);
            short8 v = {(short)u0, (short)u1, (short)u2, (short)u3,
                        (short)u4, (short)u5, (short)u6, (short)u7};
            *reinterpret_cast<short8*>(reinterpret_cast<char*>(vt) + n * 512 +
                                       ((cc * 2) ^ (((n >> 3) & 3) << 5))) = v;
        }
        __syncthreads();
        {
            int kb = lhi * 8;
            short8 af[4];
#pragma unroll
            for (int mt = 0; mt < 4; mt++)
                af[mt] = frag_ld(vt, kb, h * 128 + mhalf * 64 + mt * 16 + lrow);
#pragma unroll
            for (int nt = 0; nt < 8; nt++) {
                short8 bf = frag_ld(kt, kb, h * 128 + nt * 16 + lrow);
#pragma unroll
                for (int mt = 0; mt < 4; mt++)
                    acc[mt][nt] =
                        __builtin_amdgcn_mfma_f32_16x16x32_bf16(af[mt], bf, acc[mt][nt], 0, 0, 0);
            }
        }
        __syncthreads();
    }
    float* pb = &partial[((size_t)blockIdx.x * 2 + h) * 16384];
#pragma unroll
    for (int mt = 0; mt < 4; mt++)
#pragma unroll
        for (int reg = 0; reg < 4; reg++) {
            int c_local = mhalf * 64 + mt * 16 + lhi * 4 + reg;
#pragma unroll
            for (int nt = 0; nt < 8; nt++) pb[c_local * 128 + nt * 16 + lrow] = acc[mt][nt][reg];
        }
    {
        int cc = (t & 31) * 8;
#pragma unroll
        for (int j = 0; j < 8; j++) vred[t >> 5][cc + j] = vsum8[j];
        __syncthreads();
        float s = 0.f;
#pragma unroll
        for (int r = 0; r < 8; r++) s += vred[r][t];
        pvsum[blockIdx.x * 256 + t] = s;
    }
}

// fused kvsT + vs_sum reduction: blocks 0..127 kvsT, block 128 vs_sum
__global__ __launch_bounds__(256) void k_kvred(const float* __restrict__ partial,
                                               const float* __restrict__ pvsum, int S,
                                               unsigned short* __restrict__ kvsT,
                                               float* __restrict__ vs_sum) {
    if (blockIdx.x == 128) {
        int c = threadIdx.x;
        float s = 0.f;
        for (int i = 0; i < S; i++) s += pvsum[i * 256 + c];
        vs_sum[c] = s;
        return;
    }
    int e = blockIdx.x * 256 + threadIdx.x;  // 32768 elems
    float s = 0.f;
    for (int i = 0; i < S; i++) s += partial[(size_t)i * 32768 + e];
    kvsT[e] = f2bf(s);
}

// ---------------------------------------------------------------- GCN gather: wave-per-row, 8B/lane, 16-deep MLP
__global__ __launch_bounds__(256) void k_gather2(const unsigned short* __restrict__ prev,
                                                 const int* __restrict__ csr_src,
                                                 const int* __restrict__ offs,
                                                 const int* __restrict__ cnt,
                                                 const float* __restrict__ deg_inv,
                                                 unsigned short* __restrict__ cur, int N) {
    const int w = threadIdx.x >> 6, l = threadIdx.x & 63;
    int n = blockIdx.x * 4 + w;
    if (n >= N) return;
    const int start = offs[n], d = cnt[n];
    int e = start;
    const int eend = start + d;
    float a0 = 0.f, a1 = 0.f, a2 = 0.f, a3 = 0.f;
    const int co = l * 4;
    for (; e + 16 <= eend; e += 16) {
        int s[16];
#pragma unroll
        for (int i = 0; i < 16; i++) s[i] = csr_src[e + i];
        ushort4 u[16];
#pragma unroll
        for (int i = 0; i < 16; i++)
            u[i] = *reinterpret_cast<const ushort4*>(&prev[(size_t)s[i] * 256 + co]);
#pragma unroll
        for (int i = 0; i < 16; i++) {
            a0 += bf2f(u[i].x); a1 += bf2f(u[i].y); a2 += bf2f(u[i].z); a3 += bf2f(u[i].w);
        }
    }
    for (; e + 8 <= eend; e += 8) {
        int s[8];
#pragma unroll
        for (int i = 0; i < 8; i++) s[i] = csr_src[e + i];
        ushort4 u[8];
#pragma unroll
        for (int i = 0; i < 8; i++)
            u[i] = *reinterpret_cast<const ushort4*>(&prev[(size_t)s[i] * 256 + co]);
#pragma unroll
        for (int i = 0; i < 8; i++) {
            a0 += bf2f(u[i].x); a1 += bf2f(u[i].y); a2 += bf2f(u[i].z); a3 += bf2f(u[i].w);
        }
    }
    for (; e < eend; e++) {
        ushort4 u = *reinterpret_cast<const ushort4*>(&prev[(size_t)csr_src[e] * 256 + co]);
        a0 += bf2f(u.x); a1 += bf2f(u.y); a2 += bf2f(u.z); a3 += bf2f(u.w);
    }
    float sc = 0.5f * deg_inv[n];
    ushort4 o;
    o.x = f2bf(a0 * sc); o.y = f2bf(a1 * sc); o.z = f2bf(a2 * sc); o.w = f2bf(a3 * sc);
    *reinterpret_cast<ushort4*>(&cur[(size_t)n * 256 + co]) = o;
}

__global__ __launch_bounds__(256) void k_gather2f(const float* __restrict__ prev,
                                                  const int* __restrict__ csr_src,
                                                  const int* __restrict__ offs,
                                                  const int* __restrict__ cnt,
                                                  const float* __restrict__ deg_inv,
                                                  unsigned short* __restrict__ cur, int N) {
    const int w = threadIdx.x >> 6, l = threadIdx.x & 63;
    int n = blockIdx.x * 4 + w;
    if (n >= N) return;
    const int start = offs[n], d = cnt[n];
    int e = start;
    const int eend = start + d;
    float a0 = 0.f, a1 = 0.f;
    const int co = l * 2;
    for (; e + 16 <= eend; e += 16) {
        int s[16];
#pragma unroll
        for (int i = 0; i < 16; i++) s[i] = csr_src[e + i];
        float2 u[16];
#pragma unroll
        for (int i = 0; i < 16; i++)
            u[i] = *reinterpret_cast<const float2*>(&prev[(size_t)s[i] * 128 + co]);
#pragma unroll
        for (int i = 0; i < 16; i++) { a0 += u[i].x; a1 += u[i].y; }
    }
    for (; e + 8 <= eend; e += 8) {
        int s[8];
#pragma unroll
        for (int i = 0; i < 8; i++) s[i] = csr_src[e + i];
        float2 u[8];
#pragma unroll
        for (int i = 0; i < 8; i++)
            u[i] = *reinterpret_cast<const float2*>(&prev[(size_t)s[i] * 128 + co]);
#pragma unroll
        for (int i = 0; i < 8; i++) { a0 += u[i].x; a1 += u[i].y; }
    }
    for (; e < eend; e++) {
        float2 u = *reinterpret_cast<const float2*>(&prev[(size_t)csr_src[e] * 128 + co]);
        a0 += u.x; a1 += u.y;
    }
    float sc = 0.5f * deg_inv[n];
    ushort2 o;
    o.x = f2bf(a0 * sc); o.y = f2bf(a1 * sc);
    *reinterpret_cast<ushort2*>(&cur[(size_t)n * 256 + co]) = o;
    *reinterpret_cast<ushort2*>(&cur[(size_t)n * 256 + 128 + co]) = o;
}

// ---------------------------------------------------------------- fused: cur += (qs@kvs+vs_sum)/den ; out += 0.5*cur@Wo_blk
// cur prefetched into registers before phase-1 MFMA (T14 async-stage split).
__global__ __launch_bounds__(256) void k_att_out(const unsigned short* __restrict__ qs,
                                                 const unsigned short* __restrict__ kvsT,
                                                 const float* __restrict__ vs_sum,
                                                 const float* __restrict__ den,
                                                 unsigned short* __restrict__ cur,
                                                 const unsigned short* __restrict__ WoT,
                                                 float* __restrict__ out, int tblk, int writeCur,
                                                 int N) {
    __shared__ unsigned short sm[64 * 256];
    const int t = threadIdx.x;
    const int n0 = blockIdx.x * 64;
    // stage qs tile (64 x 256), swizzled
#pragma unroll
    for (int i = 0; i < 8; i++) {
        int chunk = i * 256 + t;
        int r = chunk >> 5, c0 = (chunk & 31) * 8;
        short8 v = {0, 0, 0, 0, 0, 0, 0, 0};
        if (n0 + r < N) v = *reinterpret_cast<const short8*>(&qs[(size_t)(n0 + r) * 256 + c0]);
        *reinterpret_cast<short8*>(reinterpret_cast<char*>(sm) + r * 512 +
                                   ((c0 * 2) ^ ((r & 7) << 4))) = v;
    }
    // prefetch cur tile into registers (latency hides under phase-1 MFMA)
    short8 cv[8];
#pragma unroll
    for (int i = 0; i < 8; i++) {
        int chunk = i * 256 + t;
        int r = chunk >> 5, c0 = (chunk & 31) * 8;
        short8 v = {0, 0, 0, 0, 0, 0, 0, 0};
        if (n0 + r < N) v = *reinterpret_cast<const short8*>(&cur[(size_t)(n0 + r) * 256 + c0]);
        cv[i] = v;
    }
    __syncthreads();
    const int w = t >> 6, l = t & 63, lrow = l & 15, lhi = l >> 4;
    const int h = w >> 1, jh = w & 1;
    const f32x4 fz = {0.f, 0.f, 0.f, 0.f};
    f32x4 acc[4][4];
#pragma unroll
    for (int mt = 0; mt < 4; mt++)
#pragma unroll
        for (int nt = 0; nt < 4; nt++) acc[mt][nt] = fz;

    for (int kk = 0; kk < 4; kk++) {
        int kb = kk * 32 + lhi * 8;
        short8 af[4];
#pragma unroll
        for (int mt = 0; mt < 4; mt++) {
            int r = mt * 16 + lrow;
            af[mt] = *reinterpret_cast<const short8*>(
                reinterpret_cast<const char*>(sm) + r * 512 +
                (((h * 128 + kb) * 2) ^ ((r & 7) << 4)));
        }
#pragma unroll
        for (int nt = 0; nt < 4; nt++) {
            int c = jh * 64 + nt * 16 + lrow;
            short8 bf = *reinterpret_cast<const short8*>(&kvsT[((size_t)h * 128 + c) * 128 + kb]);
#pragma unroll
            for (int mt = 0; mt < 4; mt++)
                acc[mt][nt] = __builtin_amdgcn_mfma_f32_16x16x32_bf16(af[mt], bf, acc[mt][nt], 0, 0, 0);
        }
    }
    __syncthreads();  // done reading qs from sm
    // write prefetched cur into sm (swizzled)
#pragma unroll
    for (int i = 0; i < 8; i++) {
        int chunk = i * 256 + t;
        int r = chunk >> 5, c0 = (chunk & 31) * 8;
        *reinterpret_cast<short8*>(reinterpret_cast<char*>(sm) + r * 512 +
                                   ((c0 * 2) ^ ((r & 7) << 4))) = cv[i];
    }
    __syncthreads();
    // phase2: sm += (attn + vs_sum)/den  (all in LDS)
#pragma unroll
    for (int mt = 0; mt < 4; mt++) {
#pragma unroll
        for (int reg = 0; reg < 4; reg++) {
            int r = mt * 16 + lhi * 4 + reg;
            int n = n0 + r;
            if (n < N) {
                float idn = 1.0f / den[n * 2 + h];
#pragma unroll
                for (int nt = 0; nt < 4; nt++) {
                    int c = h * 128 + jh * 64 + nt * 16 + lrow;
                    unsigned short* sp = reinterpret_cast<unsigned short*>(
                        reinterpret_cast<char*>(sm) + r * 512 + ((c * 2) ^ ((r & 7) << 4)));
                    float v = bf2f(*sp) + (acc[mt][nt][reg] + vs_sum[c]) * idn;
                    *sp = f2bf(v);
                }
            }
        }
    }
    __syncthreads();
    // writeback sm -> cur (coalesced); skipped on last hop (term never read again)
    if (writeCur) {
#pragma unroll
        for (int i = 0; i < 8; i++) {
            int chunk = i * 256 + t;
            int r = chunk >> 5, c0 = (chunk & 31) * 8;
            int n = n0 + r;
            if (n < N)
                *reinterpret_cast<short8*>(&cur[(size_t)n * 256 + c0]) =
                    *reinterpret_cast<const short8*>(reinterpret_cast<const char*>(sm) + r * 512 +
                                                     ((c0 * 2) ^ ((r & 7) << 4)));
        }
    }
    // phase3: out += 0.5 * sm @ WoT(tblk)
    f32x4 acc2[4][2];
#pragma unroll
    for (int mt = 0; mt < 4; mt++)
#pragma unroll
        for (int nt = 0; nt < 2; nt++) acc2[mt][nt] = fz;
    for (int kk = 0; kk < 8; kk++) {
        int kb = kk * 32 + lhi * 8;
        short8 af[4];
#pragma unroll
        for (int mt = 0; mt < 4; mt++) {
            int r = mt * 16 + lrow;
            af[mt] = *reinterpret_cast<const short8*>(
                reinterpret_cast<const char*>(sm) + r * 512 + ((kb * 2) ^ ((r & 7) << 4)));
        }
        int woff = (kb >> 7) * 640 + tblk * 128 + (kb & 127);
#pragma unroll
        for (int nt = 0; nt < 2; nt++) {
            int j = w * 32 + nt * 16 + lrow;
            short8 bf = *reinterpret_cast<const short8*>(&WoT[(size_t)j * 1280 + woff]);
#pragma unroll
            for (int mt = 0; mt < 4; mt++)
                acc2[mt][nt] = __builtin_amdgcn_mfma_f32_16x16x32_bf16(af[mt], bf, acc2[mt][nt], 0, 0, 0);
        }
    }
#pragma unroll
    for (int nt = 0; nt < 2; nt++) {
        int j = w * 32 + nt * 16 + lrow;
#pragma unroll
        for (int mt = 0; mt < 4; mt++)
#pragma unroll
            for (int reg = 0; reg < 4; reg++) {
                int n = n0 + mt * 16 + lhi * 4 + reg;
                if (n < N) out[(size_t)n * 128 + j] += 0.5f * acc2[mt][nt][reg];
            }
    }
}

// ---------------------------------------------------------------- term0: out = 0.5*([x|x]@Wo_0 + bias)
__global__ __launch_bounds__(256) void k_out0(const float* __restrict__ x,
                                              const unsigned short* __restrict__ WoT,
                                              const float* __restrict__ Wo_b,
                                              float* __restrict__ out, int N) {
    __shared__ unsigned short sm[64 * 256];
    const int t = threadIdx.x;
    const int n0 = blockIdx.x * 64;
#pragma unroll
    for (int i = 0; i < 8; i++) {
        int chunk = i * 256 + t;
        int r = chunk >> 5, c0 = (chunk & 31) * 8, cs = c0 & 127;
        float4 a0 = make_float4(0.f, 0.f, 0.f, 0.f), a1 = a0;
        if (n0 + r < N) {
            a0 = ld4f(&x[(size_t)(n0 + r) * 128 + cs]);
            a1 = ld4f(&x[(size_t)(n0 + r) * 128 + cs + 4]);
        }
        short8 v = {(short)f2bf(a0.x), (short)f2bf(a0.y), (short)f2bf(a0.z), (short)f2bf(a0.w),
                    (short)f2bf(a1.x), (short)f2bf(a1.y), (short)f2bf(a1.z), (short)f2bf(a1.w)};
        *reinterpret_cast<short8*>(reinterpret_cast<char*>(sm) + r * 512 +
                                   ((c0 * 2) ^ ((r & 7) << 4))) = v;
    }
    __syncthreads();
    const int w = t >> 6, l = t & 63, lrow = l & 15, lhi = l >> 4;
    const f32x4 fz = {0.f, 0.f, 0.f, 0.f};
    f32x4 acc2[4][2];
#pragma unroll
    for (int mt = 0; mt < 4; mt++)
#pragma unroll
        for (int nt = 0; nt < 2; nt++) acc2[mt][nt] = fz;
    for (int kk = 0; kk < 8; kk++) {
        int kb = kk * 32 + lhi * 8;
        short8 af[4];
#pragma unroll
        for (int mt = 0; mt < 4; mt++) {
            int r = mt * 16 + lrow;
            af[mt] = *reinterpret_cast<const short8*>(
                reinterpret_cast<const char*>(sm) + r * 512 + ((kb * 2) ^ ((r & 7) << 4)));
        }
        int woff = (kb >> 7) * 640 + (kb & 127);  // tblk = 0
#pragma unroll
        for (int nt = 0; nt < 2; nt++) {
            int j = w * 32 + nt * 16 + lrow;
            short8 bf = *reinterpret_cast<const short8*>(&WoT[(size_t)j * 1280 + woff]);
#pragma unroll
            for (int mt = 0; mt < 4; mt++)
                acc2[mt][nt] = __builtin_amdgcn_mfma_f32_16x16x32_bf16(af[mt], bf, acc2[mt][nt], 0, 0, 0);
        }
    }
#pragma unroll
    for (int nt = 0; nt < 2; nt++) {
        int j = w * 32 + nt * 16 + lrow;
        float b = Wo_b[j];
#pragma unroll
        for (int mt = 0; mt < 4; mt++)
#pragma unroll
            for (int reg = 0; reg < 4; reg++) {
                int n = n0 + mt * 16 + lhi * 4 + reg;
                if (n < N) out[(size_t)n * 128 + j] = 0.5f * (acc2[mt][nt][reg] + b);
            }
    }
}

// ================================================================ host
extern "C" void kernel_launch(void* const* d_in, const int* in_sizes, int n_in,
                              void* d_out, int out_size, void* d_ws, size_t ws_size,
                              hipStream_t stream) {
    const int N = in_sizes[0] / 128;
    const int E = in_sizes[1] / 2;
    const float* x = (const float*)d_in[0];
    const int* eraw = (const int*)d_in[1];
    const float* Wq_w = (const float*)d_in[2];
    const float* Wq_b = (const float*)d_in[3];
    const float* Wk_w = (const float*)d_in[4];
    const float* Wk_b = (const float*)d_in[5];
    const float* Wo_w = (const float*)d_in[6];
    const float* Wo_b = (const float*)d_in[7];
    float* out = (float*)d_out;

    char* p = (char*)d_ws;
    auto alloc = [&](size_t bytes) -> void* {
        void* r = (void*)p;
        p += (bytes + 255) & ~(size_t)255;
        return r;
    };
    unsigned short* qs = (unsigned short*)alloc((size_t)N * 256 * 2);
    unsigned short* ks = (unsigned short*)alloc((size_t)N * 256 * 2);
    unsigned short* bufA = (unsigned short*)alloc((size_t)N * 256 * 2);
    unsigned short* bufB = (unsigned short*)alloc((size_t)N * 256 * 2);
    float* deg_inv = (float*)alloc((size_t)N * 4);
    float* den = (float*)alloc((size_t)N * 2 * 4);
    float* ks_sum = (float*)alloc(256 * 4);
    float* vs_sum = (float*)alloc(256 * 4);
    float* colpart = (float*)alloc(256 * 256 * 4);
    unsigned short* WqkT = (unsigned short*)alloc(512 * 128 * 2);
    unsigned short* WoT = (unsigned short*)alloc(1280 * 128 * 2);
    unsigned short* kvsTb = (unsigned short*)alloc(32768 * 2);
    int* cnt = (int*)alloc((size_t)N * 4);
    int* offs = (int*)alloc((size_t)N * 4);
    int* gcnt = (int*)alloc(NB * 4);
    int* gbase = (int*)alloc(NB * 4);
    int* gcursor = (int*)alloc(NB * 4);
    int* mode = (int*)alloc(256);
    int* csr = (int*)alloc((size_t)E * 4);
    uint2* ebuf = (uint2*)alloc((size_t)E * 8);

    size_t used = (size_t)(p - (char*)d_ws);
    size_t rem = (ws_size > used + (1 << 20)) ? ws_size - used - (1 << 20) : 0;
    int S = (int)(rem / (32768 * 4 + 1024));
    if (S > 512) S = 512;  // 2 blocks/CU for kvs2 latency hiding
    if (S < 8) S = 8;
    float* partial = (float*)alloc((size_t)S * 32768 * 4);
    float* pvsum = (float*)alloc((size_t)S * 256 * 4);
    const int rows_per = (N + S - 1) / S;

    const int CW = (N + NB - 1) / NB;
    const int EBLK = 256;
    const int epb = (E + EBLK - 1) / EBLK;

    hipMemsetAsync(gcnt, 0, NB * 4, stream);

    k_detect<<<1, 256, 0, stream>>>(eraw, E, mode);
    k_hist<<<EBLK, 256, 0, stream>>>(eraw, E, mode, N, CW, epb, gcnt);
    k_bscan<<<1, NB, 0, stream>>>(gcnt, gbase, gcursor);
    k_part<<<EBLK, 256, 0, stream>>>(eraw, E, mode, N, CW, epb, gcursor, ebuf);
    k_build<<<NB, 256, 0, stream>>>(ebuf, gbase, gcnt, N, CW, cnt, offs, deg_inv, csr);

    k_prep_wqk<<<256, 256, 0, stream>>>(Wq_w, Wk_w, WqkT);
    k_prep_wo<<<640, 256, 0, stream>>>(Wo_w, WoT);

    const int nb64 = (N + 63) / 64;
    k_proj<<<nb64, 256, 0, stream>>>(x, WqkT, Wq_b, Wk_b, qs, ks, N);
    k_colsum<<<256, 256, 0, stream>>>(ks, N, colpart);
    k_colsum2<<<1, 256, 0, stream>>>(colpart, ks_sum);
    k_den<<<(N + 3) / 4, 256, 0, stream>>>(qs, ks_sum, den, N);
    k_out0<<<nb64, 256, 0, stream>>>(x, WoT, Wo_b, out, N);

    const int gb4 = (N + 3) / 4;

    // hop 1: prev = x (f32, stride 128, head-broadcast)
    k_kvs2<float><<<S, 256, 0, stream>>>(ks, x, 128, 127, partial, pvsum, rows_per, N);
    k_kvred<<<129, 256, 0, stream>>>(partial, pvsum, S, kvsTb, vs_sum);
    k_gather2f<<<gb4, 256, 0, stream>>>(x, csr, offs, cnt, deg_inv, bufA, N);
    k_att_out<<<nb64, 256, 0, stream>>>(qs, kvsTb, vs_sum, den, bufA, WoT, out, 1, 1, N);

    // hops 2..4
    unsigned short* prev = bufA;
    unsigned short* cur = bufB;
    for (int step = 2; step <= 4; step++) {
        k_kvs2<unsigned short><<<S, 256, 0, stream>>>(ks, prev, 256, 255, partial, pvsum, rows_per,
                                                      N);
        k_kvred<<<129, 256, 0, stream>>>(partial, pvsum, S, kvsTb, vs_sum);
        k_gather2<<<gb4, 256, 0, stream>>>(prev, csr, offs, cnt, deg_inv, cur, N);
        k_att_out<<<nb64, 256, 0, stream>>>(qs, kvsTb, vs_sum, den, cur, WoT, out, step,
                                            (step < 4) ? 1 : 0, N);
        unsigned short* tmp = prev;
        prev = cur;
        cur = tmp;
    }
}

// Round 10
// 1637.398 us; speedup vs baseline: 1.4078x; 1.1343x over previous
//
#include <hip/hip_runtime.h>

#define THREADS 256
#define NB 512
#define SEGCAP 6144

typedef __attribute__((ext_vector_type(8))) short short8;
typedef __attribute__((ext_vector_type(4))) float f32x4;

// ---------------------------------------------------------------- bf16 helpers (raw ushort storage)
__device__ __forceinline__ float bf2f(unsigned short u) {
    union { unsigned int i; float f; } v;
    v.i = ((unsigned int)u) << 16;
    return v.f;
}
__device__ __forceinline__ unsigned short f2bf(float f) {
    union { float f; unsigned int i; } v;
    v.f = f;
    unsigned int r = (v.i + 0x7FFFu + ((v.i >> 16) & 1u)) >> 16;  // RNE
    return (unsigned short)r;
}
__device__ __forceinline__ float4 ld4f(const float* p) {
    return *reinterpret_cast<const float4*>(p);
}
__device__ __forceinline__ float4 ld4f(const unsigned short* p) {
    ushort4 u = *reinterpret_cast<const ushort4*>(p);
    return make_float4(bf2f(u.x), bf2f(u.y), bf2f(u.z), bf2f(u.w));
}

// ---------------------------------------------------------------- edge accessor (int32 or int64 payload)
__device__ __forceinline__ int edge_get(const int* base, int E, int mode, int which, int e) {
    size_t idx = (size_t)which * (size_t)E + (size_t)e;
    return mode ? base[2 * idx] : base[idx];
}

__global__ __launch_bounds__(256) void k_detect(const int* __restrict__ e, int E,
                                                int* __restrict__ mode) {
    __shared__ int nz;
    if (threadIdx.x == 0) nz = 0;
    __syncthreads();
    int lim = 2 * E;
    if (lim > 8192) lim = 8192;
    for (int i = 1 + 2 * (int)threadIdx.x; i < lim; i += 512)
        if (e[i] != 0) nz = 1;
    __syncthreads();
    if (threadIdx.x == 0) *mode = (nz == 0) ? 1 : 0;
}

// ---------------------------------------------------------------- graph prep: bucket partition CSR build
__global__ __launch_bounds__(256) void k_hist(const int* __restrict__ eb, int E,
                                              const int* __restrict__ mode, int N, int CW, int epb,
                                              int* __restrict__ gcnt) {
    __shared__ int hist[NB];
    for (int i = threadIdx.x; i < NB; i += 256) hist[i] = 0;
    __syncthreads();
    int m = *mode;
    int e0 = blockIdx.x * epb;
    int e1 = min(e0 + epb, E);
    for (int e = e0 + threadIdx.x; e < e1; e += 256) {
        int c = edge_get(eb, E, m, 1, e);
        if ((unsigned)c < (unsigned)N) atomicAdd(&hist[c / CW], 1);
    }
    __syncthreads();
    for (int i = threadIdx.x; i < NB; i += 256)
        if (hist[i]) atomicAdd(&gcnt[i], hist[i]);
}

__global__ __launch_bounds__(NB) void k_bscan(const int* __restrict__ gcnt,
                                              int* __restrict__ gbase, int* __restrict__ gcursor) {
    __shared__ int s[NB];
    int t = threadIdx.x;
    int v = gcnt[t];
    s[t] = v;
    __syncthreads();
    for (int off = 1; off < NB; off <<= 1) {
        int add = (t >= off) ? s[t - off] : 0;
        __syncthreads();
        s[t] += add;
        __syncthreads();
    }
    gbase[t] = s[t] - v;
    gcursor[t] = s[t] - v;
}

__global__ __launch_bounds__(256) void k_part(const int* __restrict__ eb, int E,
                                              const int* __restrict__ mode, int N, int CW, int epb,
                                              int* __restrict__ gcursor, uint2* __restrict__ ebuf) {
    __shared__ int hist[NB];
    __shared__ int base[NB];
    for (int i = threadIdx.x; i < NB; i += 256) hist[i] = 0;
    __syncthreads();
    int m = *mode;
    int e0 = blockIdx.x * epb;
    int e1 = min(e0 + epb, E);
    for (int e = e0 + threadIdx.x; e < e1; e += 256) {
        int c = edge_get(eb, E, m, 1, e);
        if ((unsigned)c < (unsigned)N) atomicAdd(&hist[c / CW], 1);
    }
    __syncthreads();
    for (int i = threadIdx.x; i < NB; i += 256) {
        int h = hist[i];
        base[i] = h ? atomicAdd(&gcursor[i], h) : 0;
        hist[i] = 0;  // reuse as local cursor
    }
    __syncthreads();
    for (int e = e0 + threadIdx.x; e < e1; e += 256) {
        int c = edge_get(eb, E, m, 1, e);
        if ((unsigned)c < (unsigned)N) {
            int r = edge_get(eb, E, m, 0, e);
            if ((unsigned)r >= (unsigned)N) r = 0;
            int b = c / CW;
            int li = atomicAdd(&hist[b], 1);
            ebuf[(size_t)base[b] + li] = make_uint2((unsigned)r, (unsigned)c);
        }
    }
}

__global__ __launch_bounds__(256) void k_build(const uint2* __restrict__ ebuf,
                                               const int* __restrict__ gbase,
                                               const int* __restrict__ gcnt, int N, int CW,
                                               int* __restrict__ cnt, int* __restrict__ offs,
                                               float* __restrict__ deg_inv, int* __restrict__ csr) {
    __shared__ int hist[256];
    __shared__ int pfx[256];
    __shared__ int seg[SEGCAP];
    const int b = blockIdx.x;
    const int col0 = b * CW;
    const int ncols = min(CW, N - col0);
    if (ncols <= 0) return;
    const int ebase = gbase[b], ecnt = gcnt[b];
    const int t = threadIdx.x;
    for (int i = t; i < 256; i += 256) hist[i] = 0;
    __syncthreads();
    for (int e = t; e < ecnt; e += 256) {
        uint2 rc = ebuf[(size_t)ebase + e];
        atomicAdd(&hist[rc.y - col0], 1);
    }
    __syncthreads();
    int v = (t < ncols) ? hist[t] : 0;
    pfx[t] = v;
    __syncthreads();
    for (int off = 1; off < 256; off <<= 1) {
        int add = (t >= off) ? pfx[t - off] : 0;
        __syncthreads();
        pfx[t] += add;
        __syncthreads();
    }
    int excl = pfx[t] - v;
    if (t < ncols) {
        cnt[col0 + t] = v;
        offs[col0 + t] = ebase + excl;
        deg_inv[col0 + t] = (v > 0) ? 1.0f / (float)v : 0.0f;
    }
    __syncthreads();
    if (t < 256) hist[t] = (t < ncols) ? excl : 0;  // reuse as per-col cursor (bucket-local)
    __syncthreads();
    if (ecnt <= SEGCAP) {
        for (int e = t; e < ecnt; e += 256) {
            uint2 rc = ebuf[(size_t)ebase + e];
            int li = atomicAdd(&hist[rc.y - col0], 1);
            seg[li] = (int)rc.x;
        }
        __syncthreads();
        for (int e = t; e < ecnt; e += 256) csr[(size_t)ebase + e] = seg[e];
    } else {  // statistical overflow fallback
        for (int e = t; e < ecnt; e += 256) {
            uint2 rc = ebuf[(size_t)ebase + e];
            int li = atomicAdd(&hist[rc.y - col0], 1);
            csr[(size_t)ebase + li] = (int)rc.x;
        }
    }
}

// ---------------------------------------------------------------- weight prep (bf16, transposed)
__global__ __launch_bounds__(256) void k_prep_wqk(const float* __restrict__ Wq,
                                                  const float* __restrict__ Wk,
                                                  unsigned short* __restrict__ WqkT) {
    int i = blockIdx.x * 256 + threadIdx.x;  // 512*128
    if (i < 512 * 128) {
        int oc = i >> 7, k = i & 127;
        float v = (oc < 256) ? Wq[k * 256 + oc] : Wk[k * 256 + (oc - 256)];
        WqkT[i] = f2bf(v);
    }
}

__global__ __launch_bounds__(256) void k_prep_wo(const float* __restrict__ Wo,
                                                 unsigned short* __restrict__ WoT) {
    int i = blockIdx.x * 256 + threadIdx.x;  // 1280*128
    if (i < 1280 * 128) {
        int r = i >> 7, j = i & 127;
        WoT[(size_t)j * 1280 + r] = f2bf(Wo[i]);
    }
}

// Wo0 combined across heads: WoT0[j][c] = Wo[c][j] + Wo[640+c][j]
__global__ __launch_bounds__(256) void k_prep_wo0(const float* __restrict__ Wo,
                                                  unsigned short* __restrict__ WoT0) {
    int i = blockIdx.x * 256 + threadIdx.x;  // 128*128
    if (i < 16384) {
        int j = i >> 7, c = i & 127;
        WoT0[i] = f2bf(Wo[(size_t)c * 128 + j] + Wo[(size_t)(640 + c) * 128 + j]);
    }
}

// ---------------------------------------------------------------- Q/K proj + row L2-norm (MFMA, atomic-free)
__global__ __launch_bounds__(256) void k_proj(const float* __restrict__ x,
                                              const unsigned short* __restrict__ WqkT,
                                              const float* __restrict__ bq,
                                              const float* __restrict__ bk,
                                              unsigned short* __restrict__ qs,
                                              unsigned short* __restrict__ ks, int N) {
    __shared__ unsigned short xs[64 * 128];  // 16 KB input staging
    __shared__ unsigned short os[64 * 256];  // 32 KB output staging
    const int t = threadIdx.x;
    const int n0 = blockIdx.x * 64;
#pragma unroll
    for (int i = 0; i < 4; i++) {
        int chunk = i * 256 + t;
        int r = chunk >> 4, c0 = (chunk & 15) * 8;
        float4 a0 = make_float4(0.f, 0.f, 0.f, 0.f), a1 = a0;
        if (n0 + r < N) {
            a0 = ld4f(&x[(size_t)(n0 + r) * 128 + c0]);
            a1 = ld4f(&x[(size_t)(n0 + r) * 128 + c0 + 4]);
        }
        short8 v = {(short)f2bf(a0.x), (short)f2bf(a0.y), (short)f2bf(a0.z), (short)f2bf(a0.w),
                    (short)f2bf(a1.x), (short)f2bf(a1.y), (short)f2bf(a1.z), (short)f2bf(a1.w)};
        int byte = r * 256 + ((c0 * 2) ^ ((r & 7) << 4));
        *reinterpret_cast<short8*>(reinterpret_cast<char*>(xs) + byte) = v;
    }
    __syncthreads();
    const int w = t >> 6, l = t & 63, lrow = l & 15, lhi = l >> 4;
    f32x4 acc[4][8];
    const f32x4 fz = {0.f, 0.f, 0.f, 0.f};
#pragma unroll
    for (int mt = 0; mt < 4; mt++)
#pragma unroll
        for (int nt = 0; nt < 8; nt++) acc[mt][nt] = fz;

    for (int kk = 0; kk < 4; kk++) {
        int kb = kk * 32 + lhi * 8;
        short8 af[4];
#pragma unroll
        for (int mt = 0; mt < 4; mt++) {
            int r = mt * 16 + lrow;
            af[mt] = *reinterpret_cast<const short8*>(
                reinterpret_cast<const char*>(xs) + r * 256 + ((kb * 2) ^ ((r & 7) << 4)));
        }
#pragma unroll
        for (int nt = 0; nt < 8; nt++) {
            int oc = w * 128 + nt * 16 + lrow;
            short8 bf = *reinterpret_cast<const short8*>(&WqkT[(size_t)oc * 128 + kb]);
#pragma unroll
            for (int mt = 0; mt < 4; mt++)
                acc[mt][nt] = __builtin_amdgcn_mfma_f32_16x16x32_bf16(af[mt], bf, acc[mt][nt], 0, 0, 0);
        }
    }
    // bias
#pragma unroll
    for (int nt = 0; nt < 8; nt++) {
        int oc = w * 128 + nt * 16 + lrow;
        float b = (oc < 256) ? bq[oc] : bk[oc - 256];
#pragma unroll
        for (int mt = 0; mt < 4; mt++)
#pragma unroll
            for (int reg = 0; reg < 4; reg++) acc[mt][nt][reg] += b;
    }
    // row-norm in registers
    const int hc = (w & 1) * 128;
    float rv[4][4];
#pragma unroll
    for (int mt = 0; mt < 4; mt++) {
        float ss[4] = {0.f, 0.f, 0.f, 0.f};
#pragma unroll
        for (int nt = 0; nt < 8; nt++)
#pragma unroll
            for (int reg = 0; reg < 4; reg++) ss[reg] += acc[mt][nt][reg] * acc[mt][nt][reg];
#pragma unroll
        for (int m_ = 1; m_ < 16; m_ <<= 1)
#pragma unroll
            for (int reg = 0; reg < 4; reg++) ss[reg] += __shfl_xor(ss[reg], m_);
#pragma unroll
        for (int reg = 0; reg < 4; reg++) rv[mt][reg] = rsqrtf(ss[reg]);
    }
    for (int pass = 0; pass < 2; pass++) {
        if ((w >> 1) == pass) {
#pragma unroll
            for (int mt = 0; mt < 4; mt++)
#pragma unroll
                for (int reg = 0; reg < 4; reg++) {
                    int r = mt * 16 + lhi * 4 + reg;
#pragma unroll
                    for (int nt = 0; nt < 8; nt++)
                        os[r * 256 + hc + nt * 16 + lrow] = f2bf(acc[mt][nt][reg] * rv[mt][reg]);
                }
        }
        __syncthreads();
        unsigned short* dstg = pass ? ks : qs;
#pragma unroll
        for (int i = 0; i < 8; i++) {
            int chunk = i * 256 + t;
            int r = chunk >> 5, c = (chunk & 31) * 8;
            int n = n0 + r;
            if (n < N)
                *reinterpret_cast<short8*>(&dstg[(size_t)n * 256 + c]) =
                    *reinterpret_cast<const short8*>(&os[r * 256 + c]);
        }
        __syncthreads();
    }
}

// ---------------------------------------------------------------- ks_sum: 2-stage column reduction
__global__ __launch_bounds__(256) void k_colsum(const unsigned short* __restrict__ ks, int N,
                                                float* __restrict__ part) {
    const int t = threadIdx.x;
    const int stride = (N + 255) >> 8;
    int r0 = blockIdx.x * stride;
    int rend = min(r0 + stride, N);
    float s = 0.f;
    for (int n = r0; n < rend; n++) s += bf2f(ks[(size_t)n * 256 + t]);
    part[blockIdx.x * 256 + t] = s;
}

__global__ __launch_bounds__(256) void k_colsum2(const float* __restrict__ part,
                                                 float* __restrict__ ks_sum) {
    const int t = threadIdx.x;
    float s = 0.f;
    for (int b = 0; b < 256; b++) s += part[b * 256 + t];
    ks_sum[t] = s;
}

// ---------------------------------------------------------------- den = qs . ks_sum + N
__global__ __launch_bounds__(256) void k_den(const unsigned short* __restrict__ qs,
                                             const float* __restrict__ ks_sum,
                                             float* __restrict__ den, int N) {
    int w = threadIdx.x >> 6, lane = threadIdx.x & 63;
    int n = blockIdx.x * 4 + w;
    if (n >= N) return;
    float4 q = ld4f(&qs[(size_t)n * 256 + lane * 4]);
    float4 kv = *reinterpret_cast<const float4*>(&ks_sum[lane * 4]);
    float s = q.x * kv.x + q.y * kv.y + q.z * kv.z + q.w * kv.w;
#pragma unroll
    for (int off = 1; off < 32; off <<= 1) s += __shfl_xor(s, off);
    if ((lane & 31) == 0) den[n * 2 + (lane >> 5)] = s + (float)N;
}

// ---------------------------------------------------------------- kvsT = vs^T @ ks per head (MFMA split-K)
__device__ __forceinline__ short8 frag_ld(const unsigned short* tile, int kb, int col) {
    const char* b = reinterpret_cast<const char*>(tile);
    int cb = (col * 2) ^ (((kb >> 3) & 3) << 5);
    short8 r;
#pragma unroll
    for (int i = 0; i < 8; i++)
        r[i] = (short)*reinterpret_cast<const unsigned short*>(b + (kb + i) * 512 + cb);
    return r;
}

template <typename TV>
__global__ __launch_bounds__(256) void k_kvs2(const unsigned short* __restrict__ ks,
                                              const TV* __restrict__ vs, int vstride, int vmask,
                                              float* __restrict__ partial,
                                              float* __restrict__ pvsum, int rows_per, int N) {
    __shared__ unsigned short kt[32 * 256];
    __shared__ unsigned short vt[32 * 256];
    __shared__ float vred[8][256];
    const int t = threadIdx.x;
    const int w = t >> 6, l = t & 63, lrow = l & 15, lhi = l >> 4;
    const int h = w >> 1, mhalf = w & 1;
    const int r0 = blockIdx.x * rows_per;
    const int rend = min(r0 + rows_per, N);

    const f32x4 fz = {0.f, 0.f, 0.f, 0.f};
    f32x4 acc[4][8];
#pragma unroll
    for (int mt = 0; mt < 4; mt++)
#pragma unroll
        for (int nt = 0; nt < 8; nt++) acc[mt][nt] = fz;
    float vsum8[8] = {0.f, 0.f, 0.f, 0.f, 0.f, 0.f, 0.f, 0.f};

    for (int c0 = r0; c0 < rend; c0 += 32) {
#pragma unroll
        for (int i = 0; i < 4; i++) {
            int chunk = i * 256 + t;
            int n = chunk >> 5, cc = (chunk & 31) * 8;
            short8 v = {0, 0, 0, 0, 0, 0, 0, 0};
            if (c0 + n < rend)
                v = *reinterpret_cast<const short8*>(&ks[(size_t)(c0 + n) * 256 + cc]);
            *reinterpret_cast<short8*>(reinterpret_cast<char*>(kt) + n * 512 +
                                       ((cc * 2) ^ (((n >> 3) & 3) << 5))) = v;
        }
#pragma unroll
        for (int i = 0; i < 4; i++) {
            int chunk = i * 256 + t;
            int n = chunk >> 5, cc = (chunk & 31) * 8;
            float4 a0 = make_float4(0.f, 0.f, 0.f, 0.f), a1 = a0;
            if (c0 + n < rend) {
                a0 = ld4f(&vs[(size_t)(c0 + n) * vstride + (cc & vmask)]);
                a1 = ld4f(&vs[(size_t)(c0 + n) * vstride + ((cc + 4) & vmask)]);
            }
            unsigned short u0 = f2bf(a0.x), u1 = f2bf(a0.y), u2 = f2bf(a0.z), u3 = f2bf(a0.w);
            unsigned short u4 = f2bf(a1.x), u5 = f2bf(a1.y), u6 = f2bf(a1.z), u7 = f2bf(a1.w);
            vsum8[0] += bf2f(u0); vsum8[1] += bf2f(u1); vsum8[2] += bf2f(u2); vsum8[3] += bf2f(u3);
            vsum8[4] += bf2f(u4); vsum8[5] += bf2f(u5); vsum8[6] += bf2f(u6); vsum8[7] += bf2f(u7);
            short8 v = {(short)u0, (short)u1, (short)u2, (short)u3,
                        (short)u4, (short)u5, (short)u6, (short)u7};
            *reinterpret_cast<short8*>(reinterpret_cast<char*>(vt) + n * 512 +
                                       ((cc * 2) ^ (((n >> 3) & 3) << 5))) = v;
        }
        __syncthreads();
        {
            int kb = lhi * 8;
            short8 af[4];
#pragma unroll
            for (int mt = 0; mt < 4; mt++)
                af[mt] = frag_ld(vt, kb, h * 128 + mhalf * 64 + mt * 16 + lrow);
#pragma unroll
            for (int nt = 0; nt < 8; nt++) {
                short8 bf = frag_ld(kt, kb, h * 128 + nt * 16 + lrow);
#pragma unroll
                for (int mt = 0; mt < 4; mt++)
                    acc[mt][nt] =
                        __builtin_amdgcn_mfma_f32_16x16x32_bf16(af[mt], bf, acc[mt][nt], 0, 0, 0);
            }
        }
        __syncthreads();
    }
    float* pb = &partial[((size_t)blockIdx.x * 2 + h) * 16384];
#pragma unroll
    for (int mt = 0; mt < 4; mt++)
#pragma unroll
        for (int reg = 0; reg < 4; reg++) {
            int c_local = mhalf * 64 + mt * 16 + lhi * 4 + reg;
#pragma unroll
            for (int nt = 0; nt < 8; nt++) pb[c_local * 128 + nt * 16 + lrow] = acc[mt][nt][reg];
        }
    {
        int cc = (t & 31) * 8;
#pragma unroll
        for (int j = 0; j < 8; j++) vred[t >> 5][cc + j] = vsum8[j];
        __syncthreads();
        float s = 0.f;
#pragma unroll
        for (int r = 0; r < 8; r++) s += vred[r][t];
        pvsum[blockIdx.x * 256 + t] = s;
    }
}

// fused kvsT + vs_sum reduction; 8 independent accumulator chains for MLP
__global__ __launch_bounds__(256) void k_kvred(const float* __restrict__ partial,
                                               const float* __restrict__ pvsum, int S,
                                               unsigned short* __restrict__ kvsT,
                                               float* __restrict__ vs_sum) {
    if (blockIdx.x == 128) {
        int c = threadIdx.x;
        float s = 0.f;
        for (int i = 0; i < S; i++) s += pvsum[i * 256 + c];
        vs_sum[c] = s;
        return;
    }
    int e = blockIdx.x * 256 + threadIdx.x;  // 32768 elems
    float s0 = 0.f, s1 = 0.f, s2 = 0.f, s3 = 0.f, s4 = 0.f, s5 = 0.f, s6 = 0.f, s7 = 0.f;
    int i = 0;
    for (; i + 8 <= S; i += 8) {
        s0 += partial[(size_t)(i + 0) * 32768 + e];
        s1 += partial[(size_t)(i + 1) * 32768 + e];
        s2 += partial[(size_t)(i + 2) * 32768 + e];
        s3 += partial[(size_t)(i + 3) * 32768 + e];
        s4 += partial[(size_t)(i + 4) * 32768 + e];
        s5 += partial[(size_t)(i + 5) * 32768 + e];
        s6 += partial[(size_t)(i + 6) * 32768 + e];
        s7 += partial[(size_t)(i + 7) * 32768 + e];
    }
    for (; i < S; i++) s0 += partial[(size_t)i * 32768 + e];
    kvsT[e] = f2bf(((s0 + s1) + (s2 + s3)) + ((s4 + s5) + (s6 + s7)));
}

// ---------------------------------------------------------------- GCN gather: wave-per-row, 8B/lane, 16-deep MLP
__global__ __launch_bounds__(256) void k_gather2(const unsigned short* __restrict__ prev,
                                                 const int* __restrict__ csr_src,
                                                 const int* __restrict__ offs,
                                                 const int* __restrict__ cnt,
                                                 const float* __restrict__ deg_inv,
                                                 unsigned short* __restrict__ cur, int N) {
    const int w = threadIdx.x >> 6, l = threadIdx.x & 63;
    int n = blockIdx.x * 4 + w;
    if (n >= N) return;
    const int start = offs[n], d = cnt[n];
    int e = start;
    const int eend = start + d;
    float a0 = 0.f, a1 = 0.f, a2 = 0.f, a3 = 0.f;
    const int co = l * 4;
    for (; e + 16 <= eend; e += 16) {
        int s[16];
#pragma unroll
        for (int i = 0; i < 16; i++) s[i] = csr_src[e + i];
        ushort4 u[16];
#pragma unroll
        for (int i = 0; i < 16; i++)
            u[i] = *reinterpret_cast<const ushort4*>(&prev[(size_t)s[i] * 256 + co]);
#pragma unroll
        for (int i = 0; i < 16; i++) {
            a0 += bf2f(u[i].x); a1 += bf2f(u[i].y); a2 += bf2f(u[i].z); a3 += bf2f(u[i].w);
        }
    }
    for (; e + 8 <= eend; e += 8) {
        int s[8];
#pragma unroll
        for (int i = 0; i < 8; i++) s[i] = csr_src[e + i];
        ushort4 u[8];
#pragma unroll
        for (int i = 0; i < 8; i++)
            u[i] = *reinterpret_cast<const ushort4*>(&prev[(size_t)s[i] * 256 + co]);
#pragma unroll
        for (int i = 0; i < 8; i++) {
            a0 += bf2f(u[i].x); a1 += bf2f(u[i].y); a2 += bf2f(u[i].z); a3 += bf2f(u[i].w);
        }
    }
    for (; e < eend; e++) {
        ushort4 u = *reinterpret_cast<const ushort4*>(&prev[(size_t)csr_src[e] * 256 + co]);
        a0 += bf2f(u.x); a1 += bf2f(u.y); a2 += bf2f(u.z); a3 += bf2f(u.w);
    }
    float sc = 0.5f * deg_inv[n];
    ushort4 o;
    o.x = f2bf(a0 * sc); o.y = f2bf(a1 * sc); o.z = f2bf(a2 * sc); o.w = f2bf(a3 * sc);
    *reinterpret_cast<ushort4*>(&cur[(size_t)n * 256 + co]) = o;
}

__global__ __launch_bounds__(256) void k_gather2f(const float* __restrict__ prev,
                                                  const int* __restrict__ csr_src,
                                                  const int* __restrict__ offs,
                                                  const int* __restrict__ cnt,
                                                  const float* __restrict__ deg_inv,
                                                  unsigned short* __restrict__ cur, int N) {
    const int w = threadIdx.x >> 6, l = threadIdx.x & 63;
    int n = blockIdx.x * 4 + w;
    if (n >= N) return;
    const int start = offs[n], d = cnt[n];
    int e = start;
    const int eend = start + d;
    float a0 = 0.f, a1 = 0.f;
    const int co = l * 2;
    for (; e + 16 <= eend; e += 16) {
        int s[16];
#pragma unroll
        for (int i = 0; i < 16; i++) s[i] = csr_src[e + i];
        float2 u[16];
#pragma unroll
        for (int i = 0; i < 16; i++)
            u[i] = *reinterpret_cast<const float2*>(&prev[(size_t)s[i] * 128 + co]);
#pragma unroll
        for (int i = 0; i < 16; i++) { a0 += u[i].x; a1 += u[i].y; }
    }
    for (; e + 8 <= eend; e += 8) {
        int s[8];
#pragma unroll
        for (int i = 0; i < 8; i++) s[i] = csr_src[e + i];
        float2 u[8];
#pragma unroll
        for (int i = 0; i < 8; i++)
            u[i] = *reinterpret_cast<const float2*>(&prev[(size_t)s[i] * 128 + co]);
#pragma unroll
        for (int i = 0; i < 8; i++) { a0 += u[i].x; a1 += u[i].y; }
    }
    for (; e < eend; e++) {
        float2 u = *reinterpret_cast<const float2*>(&prev[(size_t)csr_src[e] * 128 + co]);
        a0 += u.x; a1 += u.y;
    }
    float sc = 0.5f * deg_inv[n];
    ushort2 o;
    o.x = f2bf(a0 * sc); o.y = f2bf(a1 * sc);
    *reinterpret_cast<ushort2*>(&cur[(size_t)n * 256 + co]) = o;
    *reinterpret_cast<ushort2*>(&cur[(size_t)n * 256 + 128 + co]) = o;
}

// ---------------------------------------------------------------- attn: cur += (qs@kvs+vs_sum)/den (no out projection)
__global__ __launch_bounds__(256) void k_att_out(const unsigned short* __restrict__ qs,
                                                 const unsigned short* __restrict__ kvsT,
                                                 const float* __restrict__ vs_sum,
                                                 const float* __restrict__ den,
                                                 unsigned short* __restrict__ cur, int N) {
    __shared__ unsigned short sm[64 * 256];
    const int t = threadIdx.x;
    const int n0 = blockIdx.x * 64;
    // stage qs tile (64 x 256), swizzled
#pragma unroll
    for (int i = 0; i < 8; i++) {
        int chunk = i * 256 + t;
        int r = chunk >> 5, c0 = (chunk & 31) * 8;
        short8 v = {0, 0, 0, 0, 0, 0, 0, 0};
        if (n0 + r < N) v = *reinterpret_cast<const short8*>(&qs[(size_t)(n0 + r) * 256 + c0]);
        *reinterpret_cast<short8*>(reinterpret_cast<char*>(sm) + r * 512 +
                                   ((c0 * 2) ^ ((r & 7) << 4))) = v;
    }
    // prefetch cur tile into registers (latency hides under MFMA)
    short8 cv[8];
#pragma unroll
    for (int i = 0; i < 8; i++) {
        int chunk = i * 256 + t;
        int r = chunk >> 5, c0 = (chunk & 31) * 8;
        short8 v = {0, 0, 0, 0, 0, 0, 0, 0};
        if (n0 + r < N) v = *reinterpret_cast<const short8*>(&cur[(size_t)(n0 + r) * 256 + c0]);
        cv[i] = v;
    }
    __syncthreads();
    const int w = t >> 6, l = t & 63, lrow = l & 15, lhi = l >> 4;
    const int h = w >> 1, jh = w & 1;
    const f32x4 fz = {0.f, 0.f, 0.f, 0.f};
    f32x4 acc[4][4];
#pragma unroll
    for (int mt = 0; mt < 4; mt++)
#pragma unroll
        for (int nt = 0; nt < 4; nt++) acc[mt][nt] = fz;

    for (int kk = 0; kk < 4; kk++) {
        int kb = kk * 32 + lhi * 8;
        short8 af[4];
#pragma unroll
        for (int mt = 0; mt < 4; mt++) {
            int r = mt * 16 + lrow;
            af[mt] = *reinterpret_cast<const short8*>(
                reinterpret_cast<const char*>(sm) + r * 512 +
                (((h * 128 + kb) * 2) ^ ((r & 7) << 4)));
        }
#pragma unroll
        for (int nt = 0; nt < 4; nt++) {
            int c = jh * 64 + nt * 16 + lrow;
            short8 bf = *reinterpret_cast<const short8*>(&kvsT[((size_t)h * 128 + c) * 128 + kb]);
#pragma unroll
            for (int mt = 0; mt < 4; mt++)
                acc[mt][nt] = __builtin_amdgcn_mfma_f32_16x16x32_bf16(af[mt], bf, acc[mt][nt], 0, 0, 0);
        }
    }
    __syncthreads();  // done reading qs from sm
    // write attn contribution (attn + vs_sum)/den into sm (bf16)
#pragma unroll
    for (int mt = 0; mt < 4; mt++) {
#pragma unroll
        for (int reg = 0; reg < 4; reg++) {
            int r = mt * 16 + lhi * 4 + reg;
            int n = n0 + r;
            if (n < N) {
                float idn = 1.0f / den[n * 2 + h];
#pragma unroll
                for (int nt = 0; nt < 4; nt++) {
                    int c = h * 128 + jh * 64 + nt * 16 + lrow;
                    unsigned short* sp = reinterpret_cast<unsigned short*>(
                        reinterpret_cast<char*>(sm) + r * 512 + ((c * 2) ^ ((r & 7) << 4)));
                    *sp = f2bf((acc[mt][nt][reg] + vs_sum[c]) * idn);
                }
            }
        }
    }
    __syncthreads();
    // final: cur = cv + contribution, coalesced store
#pragma unroll
    for (int i = 0; i < 8; i++) {
        int chunk = i * 256 + t;
        int r = chunk >> 5, c0 = (chunk & 31) * 8;
        int n = n0 + r;
        if (n < N) {
            short8 a = *reinterpret_cast<const short8*>(reinterpret_cast<const char*>(sm) +
                                                        r * 512 + ((c0 * 2) ^ ((r & 7) << 4)));
            short8 o;
#pragma unroll
            for (int j = 0; j < 8; j++)
                o[j] = (short)f2bf(bf2f((unsigned short)cv[i][j]) + bf2f((unsigned short)a[j]));
            *reinterpret_cast<short8*>(&cur[(size_t)n * 256 + c0]) = o;
        }
    }
}

// ---------------------------------------------------------------- out flush: two terms + (first: x-term + bias)
// FIRST=1: out = 0.5*([x|x]@Wo0 + tA@Wo_tblkA + tB@Wo_tblkB + bias)   (write-only)
// FIRST=0: out += 0.5*(tA@Wo_tblkA + tB@Wo_tblkB)                      (single RMW)
template <int FIRST>
__global__ __launch_bounds__(256) void k_outflush(const float* __restrict__ x,
                                                  const unsigned short* __restrict__ ta,
                                                  const unsigned short* __restrict__ tb,
                                                  const unsigned short* __restrict__ WoT,
                                                  const unsigned short* __restrict__ WoT0,
                                                  const float* __restrict__ Wo_b,
                                                  float* __restrict__ out, int tblkA, int tblkB,
                                                  int N) {
    __shared__ unsigned short sm[64 * 256];
    const int t = threadIdx.x;
    const int n0 = blockIdx.x * 64;
    const int w = t >> 6, l = t & 63, lrow = l & 15, lhi = l >> 4;
    const f32x4 fz = {0.f, 0.f, 0.f, 0.f};
    f32x4 acc2[4][2];
#pragma unroll
    for (int mt = 0; mt < 4; mt++)
#pragma unroll
        for (int nt = 0; nt < 2; nt++) acc2[mt][nt] = fz;

    if (FIRST) {
        // stage x as bf16 [64][128] (row stride 256B), swizzled
#pragma unroll
        for (int i = 0; i < 4; i++) {
            int chunk = i * 256 + t;
            int r = chunk >> 4, c0 = (chunk & 15) * 8;
            float4 a0 = make_float4(0.f, 0.f, 0.f, 0.f), a1 = a0;
            if (n0 + r < N) {
                a0 = ld4f(&x[(size_t)(n0 + r) * 128 + c0]);
                a1 = ld4f(&x[(size_t)(n0 + r) * 128 + c0 + 4]);
            }
            short8 v = {(short)f2bf(a0.x), (short)f2bf(a0.y), (short)f2bf(a0.z), (short)f2bf(a0.w),
                        (short)f2bf(a1.x), (short)f2bf(a1.y), (short)f2bf(a1.z), (short)f2bf(a1.w)};
            *reinterpret_cast<short8*>(reinterpret_cast<char*>(sm) + r * 256 +
                                       ((c0 * 2) ^ ((r & 7) << 4))) = v;
        }
        __syncthreads();
        for (int kk = 0; kk < 4; kk++) {
            int kb = kk * 32 + lhi * 8;
            short8 af[4];
#pragma unroll
            for (int mt = 0; mt < 4; mt++) {
                int r = mt * 16 + lrow;
                af[mt] = *reinterpret_cast<const short8*>(
                    reinterpret_cast<const char*>(sm) + r * 256 + ((kb * 2) ^ ((r & 7) << 4)));
            }
#pragma unroll
            for (int nt = 0; nt < 2; nt++) {
                int j = w * 32 + nt * 16 + lrow;
                short8 bf = *reinterpret_cast<const short8*>(&WoT0[(size_t)j * 128 + kb]);
#pragma unroll
                for (int mt = 0; mt < 4; mt++)
                    acc2[mt][nt] =
                        __builtin_amdgcn_mfma_f32_16x16x32_bf16(af[mt], bf, acc2[mt][nt], 0, 0, 0);
            }
        }
        __syncthreads();
    }
#pragma unroll
    for (int b = 0; b < 2; b++) {
        const unsigned short* buf = b ? tb : ta;
        const int tblk = b ? tblkB : tblkA;
        // stage term tile [64][256]
#pragma unroll
        for (int i = 0; i < 8; i++) {
            int chunk = i * 256 + t;
            int r = chunk >> 5, c0 = (chunk & 31) * 8;
            short8 v = {0, 0, 0, 0, 0, 0, 0, 0};
            if (n0 + r < N) v = *reinterpret_cast<const short8*>(&buf[(size_t)(n0 + r) * 256 + c0]);
            *reinterpret_cast<short8*>(reinterpret_cast<char*>(sm) + r * 512 +
                                       ((c0 * 2) ^ ((r & 7) << 4))) = v;
        }
        __syncthreads();
        for (int kk = 0; kk < 8; kk++) {
            int kb = kk * 32 + lhi * 8;
            short8 af[4];
#pragma unroll
            for (int mt = 0; mt < 4; mt++) {
                int r = mt * 16 + lrow;
                af[mt] = *reinterpret_cast<const short8*>(
                    reinterpret_cast<const char*>(sm) + r * 512 + ((kb * 2) ^ ((r & 7) << 4)));
            }
            int woff = (kb >> 7) * 640 + tblk * 128 + (kb & 127);
#pragma unroll
            for (int nt = 0; nt < 2; nt++) {
                int j = w * 32 + nt * 16 + lrow;
                short8 bf = *reinterpret_cast<const short8*>(&WoT[(size_t)j * 1280 + woff]);
#pragma unroll
                for (int mt = 0; mt < 4; mt++)
                    acc2[mt][nt] =
                        __builtin_amdgcn_mfma_f32_16x16x32_bf16(af[mt], bf, acc2[mt][nt], 0, 0, 0);
            }
        }
        __syncthreads();
    }
    // epilogue
#pragma unroll
    for (int nt = 0; nt < 2; nt++) {
        int j = w * 32 + nt * 16 + lrow;
        float b = FIRST ? Wo_b[j] : 0.f;
#pragma unroll
        for (int mt = 0; mt < 4; mt++)
#pragma unroll
            for (int reg = 0; reg < 4; reg++) {
                int n = n0 + mt * 16 + lhi * 4 + reg;
                if (n < N) {
                    if (FIRST)
                        out[(size_t)n * 128 + j] = 0.5f * (acc2[mt][nt][reg] + b);
                    else
                        out[(size_t)n * 128 + j] += 0.5f * acc2[mt][nt][reg];
                }
            }
    }
}

// ================================================================ host
extern "C" void kernel_launch(void* const* d_in, const int* in_sizes, int n_in,
                              void* d_out, int out_size, void* d_ws, size_t ws_size,
                              hipStream_t stream) {
    const int N = in_sizes[0] / 128;
    const int E = in_sizes[1] / 2;
    const float* x = (const float*)d_in[0];
    const int* eraw = (const int*)d_in[1];
    const float* Wq_w = (const float*)d_in[2];
    const float* Wq_b = (const float*)d_in[3];
    const float* Wk_w = (const float*)d_in[4];
    const float* Wk_b = (const float*)d_in[5];
    const float* Wo_w = (const float*)d_in[6];
    const float* Wo_b = (const float*)d_in[7];
    float* out = (float*)d_out;

    char* p = (char*)d_ws;
    auto alloc = [&](size_t bytes) -> void* {
        void* r = (void*)p;
        p += (bytes + 255) & ~(size_t)255;
        return r;
    };
    unsigned short* qs = (unsigned short*)alloc((size_t)N * 256 * 2);
    unsigned short* ks = (unsigned short*)alloc((size_t)N * 256 * 2);
    unsigned short* bufA = (unsigned short*)alloc((size_t)N * 256 * 2);
    unsigned short* bufB = (unsigned short*)alloc((size_t)N * 256 * 2);
    float* deg_inv = (float*)alloc((size_t)N * 4);
    float* den = (float*)alloc((size_t)N * 2 * 4);
    float* ks_sum = (float*)alloc(256 * 4);
    float* vs_sum = (float*)alloc(256 * 4);
    float* colpart = (float*)alloc(256 * 256 * 4);
    unsigned short* WqkT = (unsigned short*)alloc(512 * 128 * 2);
    unsigned short* WoT = (unsigned short*)alloc(1280 * 128 * 2);
    unsigned short* WoT0 = (unsigned short*)alloc(128 * 128 * 2);
    unsigned short* kvsTb = (unsigned short*)alloc(32768 * 2);
    int* cnt = (int*)alloc((size_t)N * 4);
    int* offs = (int*)alloc((size_t)N * 4);
    int* gcnt = (int*)alloc(NB * 4);
    int* gbase = (int*)alloc(NB * 4);
    int* gcursor = (int*)alloc(NB * 4);
    int* mode = (int*)alloc(256);
    int* csr = (int*)alloc((size_t)E * 4);
    uint2* ebuf = (uint2*)alloc((size_t)E * 8);

    size_t used = (size_t)(p - (char*)d_ws);
    size_t rem = (ws_size > used + (1 << 20)) ? ws_size - used - (1 << 20) : 0;
    int S = (int)(rem / (32768 * 4 + 1024));
    if (S > 256) S = 256;
    if (S < 8) S = 8;
    float* partial = (float*)alloc((size_t)S * 32768 * 4);
    float* pvsum = (float*)alloc((size_t)S * 256 * 4);
    const int rows_per = (N + S - 1) / S;

    const int CW = (N + NB - 1) / NB;
    const int EBLK = 256;
    const int epb = (E + EBLK - 1) / EBLK;

    hipMemsetAsync(gcnt, 0, NB * 4, stream);

    k_detect<<<1, 256, 0, stream>>>(eraw, E, mode);
    k_hist<<<EBLK, 256, 0, stream>>>(eraw, E, mode, N, CW, epb, gcnt);
    k_bscan<<<1, NB, 0, stream>>>(gcnt, gbase, gcursor);
    k_part<<<EBLK, 256, 0, stream>>>(eraw, E, mode, N, CW, epb, gcursor, ebuf);
    k_build<<<NB, 256, 0, stream>>>(ebuf, gbase, gcnt, N, CW, cnt, offs, deg_inv, csr);

    k_prep_wqk<<<256, 256, 0, stream>>>(Wq_w, Wk_w, WqkT);
    k_prep_wo<<<640, 256, 0, stream>>>(Wo_w, WoT);
    k_prep_wo0<<<64, 256, 0, stream>>>(Wo_w, WoT0);

    const int nb64 = (N + 63) / 64;
    k_proj<<<nb64, 256, 0, stream>>>(x, WqkT, Wq_b, Wk_b, qs, ks, N);
    k_colsum<<<256, 256, 0, stream>>>(ks, N, colpart);
    k_colsum2<<<1, 256, 0, stream>>>(colpart, ks_sum);
    k_den<<<(N + 3) / 4, 256, 0, stream>>>(qs, ks_sum, den, N);

    const int gb4 = (N + 3) / 4;

    // hop 1: prev = x (f32, head-broadcast) -> bufA (t1)
    k_kvs2<float><<<S, 256, 0, stream>>>(ks, x, 128, 127, partial, pvsum, rows_per, N);
    k_kvred<<<129, 256, 0, stream>>>(partial, pvsum, S, kvsTb, vs_sum);
    k_gather2f<<<gb4, 256, 0, stream>>>(x, csr, offs, cnt, deg_inv, bufA, N);
    k_att_out<<<nb64, 256, 0, stream>>>(qs, kvsTb, vs_sum, den, bufA, N);

    // hop 2: prev = bufA -> bufB (t2)
    k_kvs2<unsigned short><<<S, 256, 0, stream>>>(ks, bufA, 256, 255, partial, pvsum, rows_per, N);
    k_kvred<<<129, 256, 0, stream>>>(partial, pvsum, S, kvsTb, vs_sum);
    k_gather2<<<gb4, 256, 0, stream>>>(bufA, csr, offs, cnt, deg_inv, bufB, N);
    k_att_out<<<nb64, 256, 0, stream>>>(qs, kvsTb, vs_sum, den, bufB, N);

    // flush terms 0,1,2 (write-only out)
    k_outflush<1><<<nb64, 256, 0, stream>>>(x, bufA, bufB, WoT, WoT0, Wo_b, out, 1, 2, N);

    // hop 3: prev = bufB -> bufA (t3)
    k_kvs2<unsigned short><<<S, 256, 0, stream>>>(ks, bufB, 256, 255, partial, pvsum, rows_per, N);
    k_kvred<<<129, 256, 0, stream>>>(partial, pvsum, S, kvsTb, vs_sum);
    k_gather2<<<gb4, 256, 0, stream>>>(bufB, csr, offs, cnt, deg_inv, bufA, N);
    k_att_out<<<nb64, 256, 0, stream>>>(qs, kvsTb, vs_sum, den, bufA, N);

    // hop 4: prev = bufA -> bufB (t4)
    k_kvs2<unsigned short><<<S, 256, 0, stream>>>(ks, bufA, 256, 255, partial, pvsum, rows_per, N);
    k_kvred<<<129, 256, 0, stream>>>(partial, pvsum, S, kvsTb, vs_sum);
    k_gather2<<<gb4, 256, 0, stream>>>(bufA, csr, offs, cnt, deg_inv, bufB, N);
    k_att_out<<<nb64, 256, 0, stream>>>(qs, kvsTb, vs_sum, den, bufB, N);

    // flush terms 3,4 (single RMW)
    k_outflush<0><<<nb64, 256, 0, stream>>>(x, bufA, bufB, WoT, WoT0, Wo_b, out, 3, 4, N);
}

// Round 11
// 1556.378 us; speedup vs baseline: 1.4811x; 1.0521x over previous
//
#include <hip/hip_runtime.h>

#define THREADS 256
#define NB 512
#define SEGCAP 6144
#define CSB 512

typedef __attribute__((ext_vector_type(8))) short short8;
typedef __attribute__((ext_vector_type(4))) float f32x4;

// ---------------------------------------------------------------- bf16 helpers (raw ushort storage)
__device__ __forceinline__ float bf2f(unsigned short u) {
    union { unsigned int i; float f; } v;
    v.i = ((unsigned int)u) << 16;
    return v.f;
}
__device__ __forceinline__ unsigned short f2bf(float f) {
    union { float f; unsigned int i; } v;
    v.f = f;
    unsigned int r = (v.i + 0x7FFFu + ((v.i >> 16) & 1u)) >> 16;  // RNE
    return (unsigned short)r;
}
__device__ __forceinline__ float4 ld4f(const float* p) {
    return *reinterpret_cast<const float4*>(p);
}
__device__ __forceinline__ float4 ld4f(const unsigned short* p) {
    ushort4 u = *reinterpret_cast<const ushort4*>(p);
    return make_float4(bf2f(u.x), bf2f(u.y), bf2f(u.z), bf2f(u.w));
}

// ---------------------------------------------------------------- edge accessor (int32 or int64 payload)
__device__ __forceinline__ int edge_get(const int* base, int E, int mode, int which, int e) {
    size_t idx = (size_t)which * (size_t)E + (size_t)e;
    return mode ? base[2 * idx] : base[idx];
}

__global__ __launch_bounds__(256) void k_detect(const int* __restrict__ e, int E,
                                                int* __restrict__ mode) {
    __shared__ int nz;
    if (threadIdx.x == 0) nz = 0;
    __syncthreads();
    int lim = 2 * E;
    if (lim > 8192) lim = 8192;
    for (int i = 1 + 2 * (int)threadIdx.x; i < lim; i += 512)
        if (e[i] != 0) nz = 1;
    __syncthreads();
    if (threadIdx.x == 0) *mode = (nz == 0) ? 1 : 0;
}

// ---------------------------------------------------------------- graph prep: bucket partition CSR build
__global__ __launch_bounds__(256) void k_hist(const int* __restrict__ eb, int E,
                                              const int* __restrict__ mode, int N, int CW, int epb,
                                              int* __restrict__ gcnt) {
    __shared__ int hist[NB];
    for (int i = threadIdx.x; i < NB; i += 256) hist[i] = 0;
    __syncthreads();
    int m = *mode;
    int e0 = blockIdx.x * epb;
    int e1 = min(e0 + epb, E);
    for (int e = e0 + threadIdx.x; e < e1; e += 256) {
        int c = edge_get(eb, E, m, 1, e);
        if ((unsigned)c < (unsigned)N) atomicAdd(&hist[c / CW], 1);
    }
    __syncthreads();
    for (int i = threadIdx.x; i < NB; i += 256)
        if (hist[i]) atomicAdd(&gcnt[i], hist[i]);
}

__global__ __launch_bounds__(NB) void k_bscan(const int* __restrict__ gcnt,
                                              int* __restrict__ gbase, int* __restrict__ gcursor) {
    __shared__ int s[NB];
    int t = threadIdx.x;
    int v = gcnt[t];
    s[t] = v;
    __syncthreads();
    for (int off = 1; off < NB; off <<= 1) {
        int add = (t >= off) ? s[t - off] : 0;
        __syncthreads();
        s[t] += add;
        __syncthreads();
    }
    gbase[t] = s[t] - v;
    gcursor[t] = s[t] - v;
}

__global__ __launch_bounds__(256) void k_part(const int* __restrict__ eb, int E,
                                              const int* __restrict__ mode, int N, int CW, int epb,
                                              int* __restrict__ gcursor, uint2* __restrict__ ebuf) {
    __shared__ int hist[NB];
    __shared__ int base[NB];
    for (int i = threadIdx.x; i < NB; i += 256) hist[i] = 0;
    __syncthreads();
    int m = *mode;
    int e0 = blockIdx.x * epb;
    int e1 = min(e0 + epb, E);
    for (int e = e0 + threadIdx.x; e < e1; e += 256) {
        int c = edge_get(eb, E, m, 1, e);
        if ((unsigned)c < (unsigned)N) atomicAdd(&hist[c / CW], 1);
    }
    __syncthreads();
    for (int i = threadIdx.x; i < NB; i += 256) {
        int h = hist[i];
        base[i] = h ? atomicAdd(&gcursor[i], h) : 0;
        hist[i] = 0;  // reuse as local cursor
    }
    __syncthreads();
    for (int e = e0 + threadIdx.x; e < e1; e += 256) {
        int c = edge_get(eb, E, m, 1, e);
        if ((unsigned)c < (unsigned)N) {
            int r = edge_get(eb, E, m, 0, e);
            if ((unsigned)r >= (unsigned)N) r = 0;
            int b = c / CW;
            int li = atomicAdd(&hist[b], 1);
            ebuf[(size_t)base[b] + li] = make_uint2((unsigned)r, (unsigned)c);
        }
    }
}

__global__ __launch_bounds__(256) void k_build(const uint2* __restrict__ ebuf,
                                               const int* __restrict__ gbase,
                                               const int* __restrict__ gcnt, int N, int CW,
                                               int* __restrict__ cnt, int* __restrict__ offs,
                                               float* __restrict__ deg_inv, int* __restrict__ csr) {
    __shared__ int hist[256];
    __shared__ int pfx[256];
    __shared__ int seg[SEGCAP];
    const int b = blockIdx.x;
    const int col0 = b * CW;
    const int ncols = min(CW, N - col0);
    if (ncols <= 0) return;
    const int ebase = gbase[b], ecnt = gcnt[b];
    const int t = threadIdx.x;
    for (int i = t; i < 256; i += 256) hist[i] = 0;
    __syncthreads();
    for (int e = t; e < ecnt; e += 256) {
        uint2 rc = ebuf[(size_t)ebase + e];
        atomicAdd(&hist[rc.y - col0], 1);
    }
    __syncthreads();
    int v = (t < ncols) ? hist[t] : 0;
    pfx[t] = v;
    __syncthreads();
    for (int off = 1; off < 256; off <<= 1) {
        int add = (t >= off) ? pfx[t - off] : 0;
        __syncthreads();
        pfx[t] += add;
        __syncthreads();
    }
    int excl = pfx[t] - v;
    if (t < ncols) {
        cnt[col0 + t] = v;
        offs[col0 + t] = ebase + excl;
        deg_inv[col0 + t] = (v > 0) ? 1.0f / (float)v : 0.0f;
    }
    __syncthreads();
    if (t < 256) hist[t] = (t < ncols) ? excl : 0;  // reuse as per-col cursor (bucket-local)
    __syncthreads();
    if (ecnt <= SEGCAP) {
        for (int e = t; e < ecnt; e += 256) {
            uint2 rc = ebuf[(size_t)ebase + e];
            int li = atomicAdd(&hist[rc.y - col0], 1);
            seg[li] = (int)rc.x;
        }
        __syncthreads();
        for (int e = t; e < ecnt; e += 256) csr[(size_t)ebase + e] = seg[e];
    } else {  // statistical overflow fallback
        for (int e = t; e < ecnt; e += 256) {
            uint2 rc = ebuf[(size_t)ebase + e];
            int li = atomicAdd(&hist[rc.y - col0], 1);
            csr[(size_t)ebase + li] = (int)rc.x;
        }
    }
}

// ---------------------------------------------------------------- weight prep (bf16, transposed)
__global__ __launch_bounds__(256) void k_prep_wqk(const float* __restrict__ Wq,
                                                  const float* __restrict__ Wk,
                                                  unsigned short* __restrict__ WqkT) {
    int i = blockIdx.x * 256 + threadIdx.x;  // 512*128
    if (i < 512 * 128) {
        int oc = i >> 7, k = i & 127;
        float v = (oc < 256) ? Wq[k * 256 + oc] : Wk[k * 256 + (oc - 256)];
        WqkT[i] = f2bf(v);
    }
}

__global__ __launch_bounds__(256) void k_prep_wo(const float* __restrict__ Wo,
                                                 unsigned short* __restrict__ WoT) {
    int i = blockIdx.x * 256 + threadIdx.x;  // 1280*128
    if (i < 1280 * 128) {
        int r = i >> 7, j = i & 127;
        WoT[(size_t)j * 1280 + r] = f2bf(Wo[i]);
    }
}

// Wo0 combined across heads: WoT0[j][c] = Wo[c][j] + Wo[640+c][j]
__global__ __launch_bounds__(256) void k_prep_wo0(const float* __restrict__ Wo,
                                                  unsigned short* __restrict__ WoT0) {
    int i = blockIdx.x * 256 + threadIdx.x;  // 128*128
    if (i < 16384) {
        int j = i >> 7, c = i & 127;
        WoT0[i] = f2bf(Wo[(size_t)c * 128 + j] + Wo[(size_t)(640 + c) * 128 + j]);
    }
}

// ---------------------------------------------------------------- Q/K proj + row L2-norm (MFMA, atomic-free)
__global__ __launch_bounds__(256) void k_proj(const float* __restrict__ x,
                                              const unsigned short* __restrict__ WqkT,
                                              const float* __restrict__ bq,
                                              const float* __restrict__ bk,
                                              unsigned short* __restrict__ qs,
                                              unsigned short* __restrict__ ks, int N) {
    __shared__ unsigned short xs[64 * 128];  // 16 KB input staging
    __shared__ unsigned short os[64 * 256];  // 32 KB output staging
    const int t = threadIdx.x;
    const int n0 = blockIdx.x * 64;
#pragma unroll
    for (int i = 0; i < 4; i++) {
        int chunk = i * 256 + t;
        int r = chunk >> 4, c0 = (chunk & 15) * 8;
        float4 a0 = make_float4(0.f, 0.f, 0.f, 0.f), a1 = a0;
        if (n0 + r < N) {
            a0 = ld4f(&x[(size_t)(n0 + r) * 128 + c0]);
            a1 = ld4f(&x[(size_t)(n0 + r) * 128 + c0 + 4]);
        }
        short8 v = {(short)f2bf(a0.x), (short)f2bf(a0.y), (short)f2bf(a0.z), (short)f2bf(a0.w),
                    (short)f2bf(a1.x), (short)f2bf(a1.y), (short)f2bf(a1.z), (short)f2bf(a1.w)};
        int byte = r * 256 + ((c0 * 2) ^ ((r & 7) << 4));
        *reinterpret_cast<short8*>(reinterpret_cast<char*>(xs) + byte) = v;
    }
    __syncthreads();
    const int w = t >> 6, l = t & 63, lrow = l & 15, lhi = l >> 4;
    f32x4 acc[4][8];
    const f32x4 fz = {0.f, 0.f, 0.f, 0.f};
#pragma unroll
    for (int mt = 0; mt < 4; mt++)
#pragma unroll
        for (int nt = 0; nt < 8; nt++) acc[mt][nt] = fz;

    for (int kk = 0; kk < 4; kk++) {
        int kb = kk * 32 + lhi * 8;
        short8 af[4];
#pragma unroll
        for (int mt = 0; mt < 4; mt++) {
            int r = mt * 16 + lrow;
            af[mt] = *reinterpret_cast<const short8*>(
                reinterpret_cast<const char*>(xs) + r * 256 + ((kb * 2) ^ ((r & 7) << 4)));
        }
#pragma unroll
        for (int nt = 0; nt < 8; nt++) {
            int oc = w * 128 + nt * 16 + lrow;
            short8 bf = *reinterpret_cast<const short8*>(&WqkT[(size_t)oc * 128 + kb]);
#pragma unroll
            for (int mt = 0; mt < 4; mt++)
                acc[mt][nt] = __builtin_amdgcn_mfma_f32_16x16x32_bf16(af[mt], bf, acc[mt][nt], 0, 0, 0);
        }
    }
    // bias
#pragma unroll
    for (int nt = 0; nt < 8; nt++) {
        int oc = w * 128 + nt * 16 + lrow;
        float b = (oc < 256) ? bq[oc] : bk[oc - 256];
#pragma unroll
        for (int mt = 0; mt < 4; mt++)
#pragma unroll
            for (int reg = 0; reg < 4; reg++) acc[mt][nt][reg] += b;
    }
    // row-norm in registers
    const int hc = (w & 1) * 128;
    float rv[4][4];
#pragma unroll
    for (int mt = 0; mt < 4; mt++) {
        float ss[4] = {0.f, 0.f, 0.f, 0.f};
#pragma unroll
        for (int nt = 0; nt < 8; nt++)
#pragma unroll
            for (int reg = 0; reg < 4; reg++) ss[reg] += acc[mt][nt][reg] * acc[mt][nt][reg];
#pragma unroll
        for (int m_ = 1; m_ < 16; m_ <<= 1)
#pragma unroll
            for (int reg = 0; reg < 4; reg++) ss[reg] += __shfl_xor(ss[reg], m_);
#pragma unroll
        for (int reg = 0; reg < 4; reg++) rv[mt][reg] = rsqrtf(ss[reg]);
    }
    for (int pass = 0; pass < 2; pass++) {
        if ((w >> 1) == pass) {
#pragma unroll
            for (int mt = 0; mt < 4; mt++)
#pragma unroll
                for (int reg = 0; reg < 4; reg++) {
                    int r = mt * 16 + lhi * 4 + reg;
#pragma unroll
                    for (int nt = 0; nt < 8; nt++)
                        os[r * 256 + hc + nt * 16 + lrow] = f2bf(acc[mt][nt][reg] * rv[mt][reg]);
                }
        }
        __syncthreads();
        unsigned short* dstg = pass ? ks : qs;
#pragma unroll
        for (int i = 0; i < 8; i++) {
            int chunk = i * 256 + t;
            int r = chunk >> 5, c = (chunk & 31) * 8;
            int n = n0 + r;
            if (n < N)
                *reinterpret_cast<short8*>(&dstg[(size_t)n * 256 + c]) =
                    *reinterpret_cast<const short8*>(&os[r * 256 + c]);
        }
        __syncthreads();
    }
}

// ---------------------------------------------------------------- ks_sum: 2-stage column reduction (MLP-optimized)
// Block covers 8 rows/iter via short8 loads; 4-deep row unroll = 32 rows (16 KB) in flight.
__global__ __launch_bounds__(256) void k_colsum(const unsigned short* __restrict__ ks, int N,
                                                float* __restrict__ part) {
    __shared__ float red[8][256];
    const int t = threadIdx.x;
    const int rl = t >> 5;         // row lane 0..7
    const int c0 = (t & 31) * 8;   // channel base
    const int stride = (N + CSB - 1) / CSB;
    const int r0 = blockIdx.x * stride;
    const int rend = min(r0 + stride, N);
    float s[8] = {0.f, 0.f, 0.f, 0.f, 0.f, 0.f, 0.f, 0.f};
    int r = r0 + rl;
    for (; r + 24 < rend; r += 32) {
        short8 v0 = *reinterpret_cast<const short8*>(&ks[(size_t)(r + 0) * 256 + c0]);
        short8 v1 = *reinterpret_cast<const short8*>(&ks[(size_t)(r + 8) * 256 + c0]);
        short8 v2 = *reinterpret_cast<const short8*>(&ks[(size_t)(r + 16) * 256 + c0]);
        short8 v3 = *reinterpret_cast<const short8*>(&ks[(size_t)(r + 24) * 256 + c0]);
#pragma unroll
        for (int j = 0; j < 8; j++)
            s[j] += bf2f((unsigned short)v0[j]) + bf2f((unsigned short)v1[j]) +
                    bf2f((unsigned short)v2[j]) + bf2f((unsigned short)v3[j]);
    }
    for (; r < rend; r += 8) {
        short8 v = *reinterpret_cast<const short8*>(&ks[(size_t)r * 256 + c0]);
#pragma unroll
        for (int j = 0; j < 8; j++) s[j] += bf2f((unsigned short)v[j]);
    }
#pragma unroll
    for (int j = 0; j < 8; j++) red[rl][c0 + j] = s[j];
    __syncthreads();
    float tot = 0.f;
#pragma unroll
    for (int g = 0; g < 8; g++) tot += red[g][t];
    part[blockIdx.x * 256 + t] = tot;
}

__global__ __launch_bounds__(256) void k_colsum2(const float* __restrict__ part,
                                                 float* __restrict__ ks_sum) {
    const int t = threadIdx.x;
    float s0 = 0.f, s1 = 0.f, s2 = 0.f, s3 = 0.f;
    for (int b = 0; b < CSB; b += 4) {
        s0 += part[(b + 0) * 256 + t];
        s1 += part[(b + 1) * 256 + t];
        s2 += part[(b + 2) * 256 + t];
        s3 += part[(b + 3) * 256 + t];
    }
    ks_sum[t] = (s0 + s1) + (s2 + s3);
}

// ---------------------------------------------------------------- den = qs . ks_sum + N
__global__ __launch_bounds__(256) void k_den(const unsigned short* __restrict__ qs,
                                             const float* __restrict__ ks_sum,
                                             float* __restrict__ den, int N) {
    int w = threadIdx.x >> 6, lane = threadIdx.x & 63;
    int n = blockIdx.x * 4 + w;
    if (n >= N) return;
    float4 q = ld4f(&qs[(size_t)n * 256 + lane * 4]);
    float4 kv = *reinterpret_cast<const float4*>(&ks_sum[lane * 4]);
    float s = q.x * kv.x + q.y * kv.y + q.z * kv.z + q.w * kv.w;
#pragma unroll
    for (int off = 1; off < 32; off <<= 1) s += __shfl_xor(s, off);
    if ((lane & 31) == 0) den[n * 2 + (lane >> 5)] = s + (float)N;
}

// ---------------------------------------------------------------- kvsT = vs^T @ ks per head (MFMA split-K)
__device__ __forceinline__ short8 frag_ld(const unsigned short* tile, int kb, int col) {
    const char* b = reinterpret_cast<const char*>(tile);
    int cb = (col * 2) ^ (((kb >> 3) & 3) << 5);
    short8 r;
#pragma unroll
    for (int i = 0; i < 8; i++)
        r[i] = (short)*reinterpret_cast<const unsigned short*>(b + (kb + i) * 512 + cb);
    return r;
}

template <typename TV>
__global__ __launch_bounds__(256) void k_kvs2(const unsigned short* __restrict__ ks,
                                              const TV* __restrict__ vs, int vstride, int vmask,
                                              float* __restrict__ partial,
                                              float* __restrict__ pvsum, int rows_per, int N) {
    __shared__ unsigned short kt[32 * 256];
    __shared__ unsigned short vt[32 * 256];
    __shared__ float vred[8][256];
    const int t = threadIdx.x;
    const int w = t >> 6, l = t & 63, lrow = l & 15, lhi = l >> 4;
    const int h = w >> 1, mhalf = w & 1;
    const int r0 = blockIdx.x * rows_per;
    const int rend = min(r0 + rows_per, N);

    const f32x4 fz = {0.f, 0.f, 0.f, 0.f};
    f32x4 acc[4][8];
#pragma unroll
    for (int mt = 0; mt < 4; mt++)
#pragma unroll
        for (int nt = 0; nt < 8; nt++) acc[mt][nt] = fz;
    float vsum8[8] = {0.f, 0.f, 0.f, 0.f, 0.f, 0.f, 0.f, 0.f};

    for (int c0 = r0; c0 < rend; c0 += 32) {
#pragma unroll
        for (int i = 0; i < 4; i++) {
            int chunk = i * 256 + t;
            int n = chunk >> 5, cc = (chunk & 31) * 8;
            short8 v = {0, 0, 0, 0, 0, 0, 0, 0};
            if (c0 + n < rend)
                v = *reinterpret_cast<const short8*>(&ks[(size_t)(c0 + n) * 256 + cc]);
            *reinterpret_cast<short8*>(reinterpret_cast<char*>(kt) + n * 512 +
                                       ((cc * 2) ^ (((n >> 3) & 3) << 5))) = v;
        }
#pragma unroll
        for (int i = 0; i < 4; i++) {
            int chunk = i * 256 + t;
            int n = chunk >> 5, cc = (chunk & 31) * 8;
            float4 a0 = make_float4(0.f, 0.f, 0.f, 0.f), a1 = a0;
            if (c0 + n < rend) {
                a0 = ld4f(&vs[(size_t)(c0 + n) * vstride + (cc & vmask)]);
                a1 = ld4f(&vs[(size_t)(c0 + n) * vstride + ((cc + 4) & vmask)]);
            }
            unsigned short u0 = f2bf(a0.x), u1 = f2bf(a0.y), u2 = f2bf(a0.z), u3 = f2bf(a0.w);
            unsigned short u4 = f2bf(a1.x), u5 = f2bf(a1.y), u6 = f2bf(a1.z), u7 = f2bf(a1.w);
            vsum8[0] += bf2f(u0); vsum8[1] += bf2f(u1); vsum8[2] += bf2f(u2); vsum8[3] += bf2f(u3);
            vsum8[4] += bf2f(u4); vsum8[5] += bf2f(u5); vsum8[6] += bf2f(u6); vsum8[7] += bf2f(u7);
            short8 v = {(short)u0, (short)u1, (short)u2, (short)u3,
                        (short)u4, (short)u5, (short)u6, (short)u7};
            *reinterpret_cast<short8*>(reinterpret_cast<char*>(vt) + n * 512 +
                                       ((cc * 2) ^ (((n >> 3) & 3) << 5))) = v;
        }
        __syncthreads();
        {
            int kb = lhi * 8;
            short8 af[4];
#pragma unroll
            for (int mt = 0; mt < 4; mt++)
                af[mt] = frag_ld(vt, kb, h * 128 + mhalf * 64 + mt * 16 + lrow);
#pragma unroll
            for (int nt = 0; nt < 8; nt++) {
                short8 bf = frag_ld(kt, kb, h * 128 + nt * 16 + lrow);
#pragma unroll
                for (int mt = 0; mt < 4; mt++)
                    acc[mt][nt] =
                        __builtin_amdgcn_mfma_f32_16x16x32_bf16(af[mt], bf, acc[mt][nt], 0, 0, 0);
            }
        }
        __syncthreads();
    }
    float* pb = &partial[((size_t)blockIdx.x * 2 + h) * 16384];
#pragma unroll
    for (int mt = 0; mt < 4; mt++)
#pragma unroll
        for (int reg = 0; reg < 4; reg++) {
            int c_local = mhalf * 64 + mt * 16 + lhi * 4 + reg;
#pragma unroll
            for (int nt = 0; nt < 8; nt++) pb[c_local * 128 + nt * 16 + lrow] = acc[mt][nt][reg];
        }
    {
        int cc = (t & 31) * 8;
#pragma unroll
        for (int j = 0; j < 8; j++) vred[t >> 5][cc + j] = vsum8[j];
        __syncthreads();
        float s = 0.f;
#pragma unroll
        for (int r = 0; r < 8; r++) s += vred[r][t];
        pvsum[blockIdx.x * 256 + t] = s;
    }
}

// fused kvsT + vs_sum reduction; 8 independent accumulator chains for MLP
__global__ __launch_bounds__(256) void k_kvred(const float* __restrict__ partial,
                                               const float* __restrict__ pvsum, int S,
                                               unsigned short* __restrict__ kvsT,
                                               float* __restrict__ vs_sum) {
    if (blockIdx.x == 128) {
        int c = threadIdx.x;
        float s = 0.f;
        for (int i = 0; i < S; i++) s += pvsum[i * 256 + c];
        vs_sum[c] = s;
        return;
    }
    int e = blockIdx.x * 256 + threadIdx.x;  // 32768 elems
    float s0 = 0.f, s1 = 0.f, s2 = 0.f, s3 = 0.f, s4 = 0.f, s5 = 0.f, s6 = 0.f, s7 = 0.f;
    int i = 0;
    for (; i + 8 <= S; i += 8) {
        s0 += partial[(size_t)(i + 0) * 32768 + e];
        s1 += partial[(size_t)(i + 1) * 32768 + e];
        s2 += partial[(size_t)(i + 2) * 32768 + e];
        s3 += partial[(size_t)(i + 3) * 32768 + e];
        s4 += partial[(size_t)(i + 4) * 32768 + e];
        s5 += partial[(size_t)(i + 5) * 32768 + e];
        s6 += partial[(size_t)(i + 6) * 32768 + e];
        s7 += partial[(size_t)(i + 7) * 32768 + e];
    }
    for (; i < S; i++) s0 += partial[(size_t)i * 32768 + e];
    kvsT[e] = f2bf(((s0 + s1) + (s2 + s3)) + ((s4 + s5) + (s6 + s7)));
}

// ---------------------------------------------------------------- GCN gather: wave-per-row, 8B/lane, 16-deep MLP
__global__ __launch_bounds__(256) void k_gather2(const unsigned short* __restrict__ prev,
                                                 const int* __restrict__ csr_src,
                                                 const int* __restrict__ offs,
                                                 const int* __restrict__ cnt,
                                                 const float* __restrict__ deg_inv,
                                                 unsigned short* __restrict__ cur, int N) {
    const int w = threadIdx.x >> 6, l = threadIdx.x & 63;
    int n = blockIdx.x * 4 + w;
    if (n >= N) return;
    const int start = offs[n], d = cnt[n];
    int e = start;
    const int eend = start + d;
    float a0 = 0.f, a1 = 0.f, a2 = 0.f, a3 = 0.f;
    const int co = l * 4;
    for (; e + 16 <= eend; e += 16) {
        int s[16];
#pragma unroll
        for (int i = 0; i < 16; i++) s[i] = csr_src[e + i];
        ushort4 u[16];
#pragma unroll
        for (int i = 0; i < 16; i++)
            u[i] = *reinterpret_cast<const ushort4*>(&prev[(size_t)s[i] * 256 + co]);
#pragma unroll
        for (int i = 0; i < 16; i++) {
            a0 += bf2f(u[i].x); a1 += bf2f(u[i].y); a2 += bf2f(u[i].z); a3 += bf2f(u[i].w);
        }
    }
    for (; e + 8 <= eend; e += 8) {
        int s[8];
#pragma unroll
        for (int i = 0; i < 8; i++) s[i] = csr_src[e + i];
        ushort4 u[8];
#pragma unroll
        for (int i = 0; i < 8; i++)
            u[i] = *reinterpret_cast<const ushort4*>(&prev[(size_t)s[i] * 256 + co]);
#pragma unroll
        for (int i = 0; i < 8; i++) {
            a0 += bf2f(u[i].x); a1 += bf2f(u[i].y); a2 += bf2f(u[i].z); a3 += bf2f(u[i].w);
        }
    }
    for (; e < eend; e++) {
        ushort4 u = *reinterpret_cast<const ushort4*>(&prev[(size_t)csr_src[e] * 256 + co]);
        a0 += bf2f(u.x); a1 += bf2f(u.y); a2 += bf2f(u.z); a3 += bf2f(u.w);
    }
    float sc = 0.5f * deg_inv[n];
    ushort4 o;
    o.x = f2bf(a0 * sc); o.y = f2bf(a1 * sc); o.z = f2bf(a2 * sc); o.w = f2bf(a3 * sc);
    *reinterpret_cast<ushort4*>(&cur[(size_t)n * 256 + co]) = o;
}

__global__ __launch_bounds__(256) void k_gather2f(const float* __restrict__ prev,
                                                  const int* __restrict__ csr_src,
                                                  const int* __restrict__ offs,
                                                  const int* __restrict__ cnt,
                                                  const float* __restrict__ deg_inv,
                                                  unsigned short* __restrict__ cur, int N) {
    const int w = threadIdx.x >> 6, l = threadIdx.x & 63;
    int n = blockIdx.x * 4 + w;
    if (n >= N) return;
    const int start = offs[n], d = cnt[n];
    int e = start;
    const int eend = start + d;
    float a0 = 0.f, a1 = 0.f;
    const int co = l * 2;
    for (; e + 16 <= eend; e += 16) {
        int s[16];
#pragma unroll
        for (int i = 0; i < 16; i++) s[i] = csr_src[e + i];
        float2 u[16];
#pragma unroll
        for (int i = 0; i < 16; i++)
            u[i] = *reinterpret_cast<const float2*>(&prev[(size_t)s[i] * 128 + co]);
#pragma unroll
        for (int i = 0; i < 16; i++) { a0 += u[i].x; a1 += u[i].y; }
    }
    for (; e + 8 <= eend; e += 8) {
        int s[8];
#pragma unroll
        for (int i = 0; i < 8; i++) s[i] = csr_src[e + i];
        float2 u[8];
#pragma unroll
        for (int i = 0; i < 8; i++)
            u[i] = *reinterpret_cast<const float2*>(&prev[(size_t)s[i] * 128 + co]);
#pragma unroll
        for (int i = 0; i < 8; i++) { a0 += u[i].x; a1 += u[i].y; }
    }
    for (; e < eend; e++) {
        float2 u = *reinterpret_cast<const float2*>(&prev[(size_t)csr_src[e] * 128 + co]);
        a0 += u.x; a1 += u.y;
    }
    float sc = 0.5f * deg_inv[n];
    ushort2 o;
    o.x = f2bf(a0 * sc); o.y = f2bf(a1 * sc);
    *reinterpret_cast<ushort2*>(&cur[(size_t)n * 256 + co]) = o;
    *reinterpret_cast<ushort2*>(&cur[(size_t)n * 256 + 128 + co]) = o;
}

// ---------------------------------------------------------------- attn: cur += (qs@kvs+vs_sum)/den (no out projection)
__global__ __launch_bounds__(256) void k_att_out(const unsigned short* __restrict__ qs,
                                                 const unsigned short* __restrict__ kvsT,
                                                 const float* __restrict__ vs_sum,
                                                 const float* __restrict__ den,
                                                 unsigned short* __restrict__ cur, int N) {
    __shared__ unsigned short sm[64 * 256];
    const int t = threadIdx.x;
    const int n0 = blockIdx.x * 64;
    // stage qs tile (64 x 256), swizzled
#pragma unroll
    for (int i = 0; i < 8; i++) {
        int chunk = i * 256 + t;
        int r = chunk >> 5, c0 = (chunk & 31) * 8;
        short8 v = {0, 0, 0, 0, 0, 0, 0, 0};
        if (n0 + r < N) v = *reinterpret_cast<const short8*>(&qs[(size_t)(n0 + r) * 256 + c0]);
        *reinterpret_cast<short8*>(reinterpret_cast<char*>(sm) + r * 512 +
                                   ((c0 * 2) ^ ((r & 7) << 4))) = v;
    }
    // prefetch cur tile into registers (latency hides under MFMA)
    short8 cv[8];
#pragma unroll
    for (int i = 0; i < 8; i++) {
        int chunk = i * 256 + t;
        int r = chunk >> 5, c0 = (chunk & 31) * 8;
        short8 v = {0, 0, 0, 0, 0, 0, 0, 0};
        if (n0 + r < N) v = *reinterpret_cast<const short8*>(&cur[(size_t)(n0 + r) * 256 + c0]);
        cv[i] = v;
    }
    __syncthreads();
    const int w = t >> 6, l = t & 63, lrow = l & 15, lhi = l >> 4;
    const int h = w >> 1, jh = w & 1;
    const f32x4 fz = {0.f, 0.f, 0.f, 0.f};
    f32x4 acc[4][4];
#pragma unroll
    for (int mt = 0; mt < 4; mt++)
#pragma unroll
        for (int nt = 0; nt < 4; nt++) acc[mt][nt] = fz;

    for (int kk = 0; kk < 4; kk++) {
        int kb = kk * 32 + lhi * 8;
        short8 af[4];
#pragma unroll
        for (int mt = 0; mt < 4; mt++) {
            int r = mt * 16 + lrow;
            af[mt] = *reinterpret_cast<const short8*>(
                reinterpret_cast<const char*>(sm) + r * 512 +
                (((h * 128 + kb) * 2) ^ ((r & 7) << 4)));
        }
#pragma unroll
        for (int nt = 0; nt < 4; nt++) {
            int c = jh * 64 + nt * 16 + lrow;
            short8 bf = *reinterpret_cast<const short8*>(&kvsT[((size_t)h * 128 + c) * 128 + kb]);
#pragma unroll
            for (int mt = 0; mt < 4; mt++)
                acc[mt][nt] = __builtin_amdgcn_mfma_f32_16x16x32_bf16(af[mt], bf, acc[mt][nt], 0, 0, 0);
        }
    }
    __syncthreads();  // done reading qs from sm
    // write attn contribution (attn + vs_sum)/den into sm (bf16)
#pragma unroll
    for (int mt = 0; mt < 4; mt++) {
#pragma unroll
        for (int reg = 0; reg < 4; reg++) {
            int r = mt * 16 + lhi * 4 + reg;
            int n = n0 + r;
            if (n < N) {
                float idn = 1.0f / den[n * 2 + h];
#pragma unroll
                for (int nt = 0; nt < 4; nt++) {
                    int c = h * 128 + jh * 64 + nt * 16 + lrow;
                    unsigned short* sp = reinterpret_cast<unsigned short*>(
                        reinterpret_cast<char*>(sm) + r * 512 + ((c * 2) ^ ((r & 7) << 4)));
                    *sp = f2bf((acc[mt][nt][reg] + vs_sum[c]) * idn);
                }
            }
        }
    }
    __syncthreads();
    // final: cur = cv + contribution, coalesced store
#pragma unroll
    for (int i = 0; i < 8; i++) {
        int chunk = i * 256 + t;
        int r = chunk >> 5, c0 = (chunk & 31) * 8;
        int n = n0 + r;
        if (n < N) {
            short8 a = *reinterpret_cast<const short8*>(reinterpret_cast<const char*>(sm) +
                                                        r * 512 + ((c0 * 2) ^ ((r & 7) << 4)));
            short8 o;
#pragma unroll
            for (int j = 0; j < 8; j++)
                o[j] = (short)f2bf(bf2f((unsigned short)cv[i][j]) + bf2f((unsigned short)a[j]));
            *reinterpret_cast<short8*>(&cur[(size_t)n * 256 + c0]) = o;
        }
    }
}

// ---------------------------------------------------------------- out flush: two terms + (first: x-term + bias)
template <int FIRST>
__global__ __launch_bounds__(256) void k_outflush(const float* __restrict__ x,
                                                  const unsigned short* __restrict__ ta,
                                                  const unsigned short* __restrict__ tb,
                                                  const unsigned short* __restrict__ WoT,
                                                  const unsigned short* __restrict__ WoT0,
                                                  const float* __restrict__ Wo_b,
                                                  float* __restrict__ out, int tblkA, int tblkB,
                                                  int N) {
    __shared__ unsigned short sm[64 * 256];
    const int t = threadIdx.x;
    const int n0 = blockIdx.x * 64;
    const int w = t >> 6, l = t & 63, lrow = l & 15, lhi = l >> 4;
    const f32x4 fz = {0.f, 0.f, 0.f, 0.f};
    f32x4 acc2[4][2];
#pragma unroll
    for (int mt = 0; mt < 4; mt++)
#pragma unroll
        for (int nt = 0; nt < 2; nt++) acc2[mt][nt] = fz;

    if (FIRST) {
#pragma unroll
        for (int i = 0; i < 4; i++) {
            int chunk = i * 256 + t;
            int r = chunk >> 4, c0 = (chunk & 15) * 8;
            float4 a0 = make_float4(0.f, 0.f, 0.f, 0.f), a1 = a0;
            if (n0 + r < N) {
                a0 = ld4f(&x[(size_t)(n0 + r) * 128 + c0]);
                a1 = ld4f(&x[(size_t)(n0 + r) * 128 + c0 + 4]);
            }
            short8 v = {(short)f2bf(a0.x), (short)f2bf(a0.y), (short)f2bf(a0.z), (short)f2bf(a0.w),
                        (short)f2bf(a1.x), (short)f2bf(a1.y), (short)f2bf(a1.z), (short)f2bf(a1.w)};
            *reinterpret_cast<short8*>(reinterpret_cast<char*>(sm) + r * 256 +
                                       ((c0 * 2) ^ ((r & 7) << 4))) = v;
        }
        __syncthreads();
        for (int kk = 0; kk < 4; kk++) {
            int kb = kk * 32 + lhi * 8;
            short8 af[4];
#pragma unroll
            for (int mt = 0; mt < 4; mt++) {
                int r = mt * 16 + lrow;
                af[mt] = *reinterpret_cast<const short8*>(
                    reinterpret_cast<const char*>(sm) + r * 256 + ((kb * 2) ^ ((r & 7) << 4)));
            }
#pragma unroll
            for (int nt = 0; nt < 2; nt++) {
                int j = w * 32 + nt * 16 + lrow;
                short8 bf = *reinterpret_cast<const short8*>(&WoT0[(size_t)j * 128 + kb]);
#pragma unroll
                for (int mt = 0; mt < 4; mt++)
                    acc2[mt][nt] =
                        __builtin_amdgcn_mfma_f32_16x16x32_bf16(af[mt], bf, acc2[mt][nt], 0, 0, 0);
            }
        }
        __syncthreads();
    }
#pragma unroll
    for (int b = 0; b < 2; b++) {
        const unsigned short* buf = b ? tb : ta;
        const int tblk = b ? tblkB : tblkA;
#pragma unroll
        for (int i = 0; i < 8; i++) {
            int chunk = i * 256 + t;
            int r = chunk >> 5, c0 = (chunk & 31) * 8;
            short8 v = {0, 0, 0, 0, 0, 0, 0, 0};
            if (n0 + r < N) v = *reinterpret_cast<const short8*>(&buf[(size_t)(n0 + r) * 256 + c0]);
            *reinterpret_cast<short8*>(reinterpret_cast<char*>(sm) + r * 512 +
                                       ((c0 * 2) ^ ((r & 7) << 4))) = v;
        }
        __syncthreads();
        for (int kk = 0; kk < 8; kk++) {
            int kb = kk * 32 + lhi * 8;
            short8 af[4];
#pragma unroll
            for (int mt = 0; mt < 4; mt++) {
                int r = mt * 16 + lrow;
                af[mt] = *reinterpret_cast<const short8*>(
                    reinterpret_cast<const char*>(sm) + r * 512 + ((kb * 2) ^ ((r & 7) << 4)));
            }
            int woff = (kb >> 7) * 640 + tblk * 128 + (kb & 127);
#pragma unroll
            for (int nt = 0; nt < 2; nt++) {
                int j = w * 32 + nt * 16 + lrow;
                short8 bf = *reinterpret_cast<const short8*>(&WoT[(size_t)j * 1280 + woff]);
#pragma unroll
                for (int mt = 0; mt < 4; mt++)
                    acc2[mt][nt] =
                        __builtin_amdgcn_mfma_f32_16x16x32_bf16(af[mt], bf, acc2[mt][nt], 0, 0, 0);
            }
        }
        __syncthreads();
    }
    // epilogue
#pragma unroll
    for (int nt = 0; nt < 2; nt++) {
        int j = w * 32 + nt * 16 + lrow;
        float b = FIRST ? Wo_b[j] : 0.f;
#pragma unroll
        for (int mt = 0; mt < 4; mt++)
#pragma unroll
            for (int reg = 0; reg < 4; reg++) {
                int n = n0 + mt * 16 + lhi * 4 + reg;
                if (n < N) {
                    if (FIRST)
                        out[(size_t)n * 128 + j] = 0.5f * (acc2[mt][nt][reg] + b);
                    else
                        out[(size_t)n * 128 + j] += 0.5f * acc2[mt][nt][reg];
                }
            }
    }
}

// ================================================================ host
extern "C" void kernel_launch(void* const* d_in, const int* in_sizes, int n_in,
                              void* d_out, int out_size, void* d_ws, size_t ws_size,
                              hipStream_t stream) {
    const int N = in_sizes[0] / 128;
    const int E = in_sizes[1] / 2;
    const float* x = (const float*)d_in[0];
    const int* eraw = (const int*)d_in[1];
    const float* Wq_w = (const float*)d_in[2];
    const float* Wq_b = (const float*)d_in[3];
    const float* Wk_w = (const float*)d_in[4];
    const float* Wk_b = (const float*)d_in[5];
    const float* Wo_w = (const float*)d_in[6];
    const float* Wo_b = (const float*)d_in[7];
    float* out = (float*)d_out;

    char* p = (char*)d_ws;
    auto alloc = [&](size_t bytes) -> void* {
        void* r = (void*)p;
        p += (bytes + 255) & ~(size_t)255;
        return r;
    };
    unsigned short* qs = (unsigned short*)alloc((size_t)N * 256 * 2);
    unsigned short* ks = (unsigned short*)alloc((size_t)N * 256 * 2);
    unsigned short* bufA = (unsigned short*)alloc((size_t)N * 256 * 2);
    unsigned short* bufB = (unsigned short*)alloc((size_t)N * 256 * 2);
    float* deg_inv = (float*)alloc((size_t)N * 4);
    float* den = (float*)alloc((size_t)N * 2 * 4);
    float* ks_sum = (float*)alloc(256 * 4);
    float* vs_sum = (float*)alloc(256 * 4);
    float* colpart = (float*)alloc((size_t)CSB * 256 * 4);
    unsigned short* WqkT = (unsigned short*)alloc(512 * 128 * 2);
    unsigned short* WoT = (unsigned short*)alloc(1280 * 128 * 2);
    unsigned short* WoT0 = (unsigned short*)alloc(128 * 128 * 2);
    unsigned short* kvsTb = (unsigned short*)alloc(32768 * 2);
    int* cnt = (int*)alloc((size_t)N * 4);
    int* offs = (int*)alloc((size_t)N * 4);
    int* gcnt = (int*)alloc(NB * 4);
    int* gbase = (int*)alloc(NB * 4);
    int* gcursor = (int*)alloc(NB * 4);
    int* mode = (int*)alloc(256);
    int* csr = (int*)alloc((size_t)E * 4);
    uint2* ebuf = (uint2*)alloc((size_t)E * 8);

    size_t used = (size_t)(p - (char*)d_ws);
    size_t rem = (ws_size > used + (1 << 20)) ? ws_size - used - (1 << 20) : 0;
    int S = (int)(rem / (32768 * 4 + 1024));
    if (S > 256) S = 256;
    if (S < 8) S = 8;
    float* partial = (float*)alloc((size_t)S * 32768 * 4);
    float* pvsum = (float*)alloc((size_t)S * 256 * 4);
    const int rows_per = (N + S - 1) / S;

    const int CW = (N + NB - 1) / NB;
    const int EBLK = 256;
    const int epb = (E + EBLK - 1) / EBLK;

    hipMemsetAsync(gcnt, 0, NB * 4, stream);

    k_detect<<<1, 256, 0, stream>>>(eraw, E, mode);
    k_hist<<<EBLK, 256, 0, stream>>>(eraw, E, mode, N, CW, epb, gcnt);
    k_bscan<<<1, NB, 0, stream>>>(gcnt, gbase, gcursor);
    k_part<<<EBLK, 256, 0, stream>>>(eraw, E, mode, N, CW, epb, gcursor, ebuf);
    k_build<<<NB, 256, 0, stream>>>(ebuf, gbase, gcnt, N, CW, cnt, offs, deg_inv, csr);

    k_prep_wqk<<<256, 256, 0, stream>>>(Wq_w, Wk_w, WqkT);
    k_prep_wo<<<640, 256, 0, stream>>>(Wo_w, WoT);
    k_prep_wo0<<<64, 256, 0, stream>>>(Wo_w, WoT0);

    const int nb64 = (N + 63) / 64;
    k_proj<<<nb64, 256, 0, stream>>>(x, WqkT, Wq_b, Wk_b, qs, ks, N);
    k_colsum<<<CSB, 256, 0, stream>>>(ks, N, colpart);
    k_colsum2<<<1, 256, 0, stream>>>(colpart, ks_sum);
    k_den<<<(N + 3) / 4, 256, 0, stream>>>(qs, ks_sum, den, N);

    const int gb4 = (N + 3) / 4;

    // hop 1: prev = x (f32, head-broadcast) -> bufA (t1)
    k_kvs2<float><<<S, 256, 0, stream>>>(ks, x, 128, 127, partial, pvsum, rows_per, N);
    k_kvred<<<129, 256, 0, stream>>>(partial, pvsum, S, kvsTb, vs_sum);
    k_gather2f<<<gb4, 256, 0, stream>>>(x, csr, offs, cnt, deg_inv, bufA, N);
    k_att_out<<<nb64, 256, 0, stream>>>(qs, kvsTb, vs_sum, den, bufA, N);

    // hop 2: prev = bufA -> bufB (t2)
    k_kvs2<unsigned short><<<S, 256, 0, stream>>>(ks, bufA, 256, 255, partial, pvsum, rows_per, N);
    k_kvred<<<129, 256, 0, stream>>>(partial, pvsum, S, kvsTb, vs_sum);
    k_gather2<<<gb4, 256, 0, stream>>>(bufA, csr, offs, cnt, deg_inv, bufB, N);
    k_att_out<<<nb64, 256, 0, stream>>>(qs, kvsTb, vs_sum, den, bufB, N);

    // flush terms 0,1,2 (write-only out)
    k_outflush<1><<<nb64, 256, 0, stream>>>(x, bufA, bufB, WoT, WoT0, Wo_b, out, 1, 2, N);

    // hop 3: prev = bufB -> bufA (t3)
    k_kvs2<unsigned short><<<S, 256, 0, stream>>>(ks, bufB, 256, 255, partial, pvsum, rows_per, N);
    k_kvred<<<129, 256, 0, stream>>>(partial, pvsum, S, kvsTb, vs_sum);
    k_gather2<<<gb4, 256, 0, stream>>>(bufB, csr, offs, cnt, deg_inv, bufA, N);
    k_att_out<<<nb64, 256, 0, stream>>>(qs, kvsTb, vs_sum, den, bufA, N);

    // hop 4: prev = bufA -> bufB (t4)
    k_kvs2<unsigned short><<<S, 256, 0, stream>>>(ks, bufA, 256, 255, partial, pvsum, rows_per, N);
    k_kvred<<<129, 256, 0, stream>>>(partial, pvsum, S, kvsTb, vs_sum);
    k_gather2<<<gb4, 256, 0, stream>>>(bufA, csr, offs, cnt, deg_inv, bufB, N);
    k_att_out<<<nb64, 256, 0, stream>>>(qs, kvsTb, vs_sum, den, bufB, N);

    // flush terms 3,4 (single RMW)
    k_outflush<0><<<nb64, 256, 0, stream>>>(x, bufA, bufB, WoT, WoT0, Wo_b, out, 3, 4, N);
}